// Round 3
// baseline (474.259 us; speedup 1.0000x reference)
//
#include <hip/hip_runtime.h>
#include <cstdint>

// ---------------------------------------------------------------------------
// MixedMHA: x[8,1024,1024] -> (output, k, v), causal MHA with per-token
// dedicated QKV weights for the first 16 tokens.
// Round 3: replace both 128x128 m97-structure GEMMs with an 8-phase
// counted-vmcnt GEMM (T3+T4+T5): BM=128 BN=256 BK=64, 8 waves, 4 phases per
// K-tile, one-tile-ahead staging with vmcnt(3) gates (never drain-to-0 in the
// main loop), raw s_barrier + compiler fences, setprio around MFMA clusters.
// Grid shapes chosen for exact occupancy rounds: MODE0 768 blocks (3 rounds),
// MODE1 256 blocks (1 round) at 1 block/CU (96 KB LDS).
// Other kernels byte-identical to round 2 (proven).
// ---------------------------------------------------------------------------

typedef unsigned short u16;
typedef __attribute__((ext_vector_type(8)))  __bf16 bf16x8;
typedef __attribute__((ext_vector_type(8)))  u16    u16x8;
typedef __attribute__((ext_vector_type(4)))  float  f32x4;

#define BSD   (8u * 1024u * 1024u)      // one [B,S,D] section in d_out
#define QSCALE 0.18033688011112042f     // 0.125 * log2(e): softmax in exp2 units

__device__ __forceinline__ u16 f2bf(float f) {
    unsigned u = __builtin_bit_cast(unsigned, f);
    u += 0x7fffu + ((u >> 16) & 1u);            // RNE
    return (u16)(u >> 16);
}

// pack hi16(p1):hi16(p0) in one v_perm_b32 (bf16 truncation)
__device__ __forceinline__ unsigned pack_bf2(float p0, float p1) {
    return __builtin_amdgcn_perm(__builtin_bit_cast(unsigned, p1),
                                 __builtin_bit_cast(unsigned, p0), 0x07060302u);
}

__device__ __forceinline__ void gl_lds16(const void* g, void* l) {
    __builtin_amdgcn_global_load_lds(
        (const __attribute__((address_space(1))) unsigned*)g,
        (__attribute__((address_space(3))) unsigned*)l, 16, 0, 0);
}

#define FENCE asm volatile("" ::: "memory")
#define WAITV(n) asm volatile("s_waitcnt vmcnt(" #n ")" ::: "memory")

// ---------------------------------------------------------------------------
// 1. Fused converts (independent block families, no shared state).
// ---------------------------------------------------------------------------
__global__ __launch_bounds__(256) void cvt_fused(
        const float* __restrict__ Wq, const float* __restrict__ Wk,
        const float* __restrict__ Wv, const float* __restrict__ Wo,
        u16* __restrict__ WTcat, u16* __restrict__ WoT,
        const float4* __restrict__ x, u16* __restrict__ xb) {
    __shared__ float t[32][33];
    int z = blockIdx.z;
    if (z < 4) {
        const float* src = (z == 0) ? Wq : (z == 1) ? Wk : (z == 2) ? Wv : Wo;
        u16* dst = (z < 3) ? (WTcat + (size_t)z * 1024 * 1024) : WoT;
        int k0 = blockIdx.x * 32, n0 = blockIdx.y * 32;
        int xx = threadIdx.x & 31, yy = threadIdx.x >> 5;   // 32 x 8
#pragma unroll
        for (int i = 0; i < 4; ++i)
            t[yy + 8 * i][xx] = src[(size_t)(k0 + yy + 8 * i) * 1024 + n0 + xx];
        __syncthreads();
#pragma unroll
        for (int i = 0; i < 4; ++i)
            dst[(size_t)(n0 + yy + 8 * i) * 1024 + k0 + xx] = f2bf(t[xx][yy + 8 * i]);
    } else {
        int lb = (z - 4) * 1024 + blockIdx.y * 32 + blockIdx.x;  // 8192 blocks
        int i = lb * 256 + threadIdx.x;                          // 2M float4
        float4 v = x[i];
        ushort4 o;
        o.x = f2bf(v.x); o.y = f2bf(v.y); o.z = f2bf(v.z); o.w = f2bf(v.w);
        ((ushort4*)xb)[i] = o;
    }
}

// ---------------------------------------------------------------------------
// 2./6. 8-phase GEMM: C = A[8192,1024] * Bt[N,1024]^T, BM=128 BN=256 BK=64.
// 8 waves (2M x 4N); per-wave C = 64x64 (acc f32x4[4][4]).
// Per K-tile: 4 phases = C-quadrants (mh,nh) in order (0,0),(1,0),(1,1),(0,1);
// each phase: 8 ds_read_b128 -> stage 1 unit of tile t+1 -> [vmcnt gate] ->
// barrier -> lgkmcnt(0) -> setprio(1) 8 MFMA setprio(0) -> barrier.
// Stage units (consumption sets): SA0=A rows{0-31,64-95}, SA1=A{32-63,96-127},
// SB0=B rows{s*64+0..31}, SB1=B{s*64+32..63}; staged at phases 1,2,3,4 of the
// PREVIOUS tile. Gates vmcnt(3) at phases 1,2,4 (in-order retirement makes
// exactly the needed units resident); never 0 in main loop.
// MODE 0: fused QKV epilogue (N=3072). MODE 1: plain fp32 out (N=1024).
// ---------------------------------------------------------------------------
#define LDfrag(BUF, bufi, row, ks)                                            \
    __builtin_bit_cast(bf16x8, *(const u16x8*)&BUF[bufi]                      \
        [(row) * 64 + ((((ks) * 4 + kg) ^ ((row) & 7)) * 8)])

#define PH(bufi, mh, nh, STAGE_STMT, GATE_STMT) do {                          \
    bf16x8 af_[2][2], bq_[2][2];                                              \
    _Pragma("unroll") for (int mi = 0; mi < 2; ++mi) {                        \
        int arow = wm * 64 + (mh) * 32 + mi * 16 + lr;                        \
        _Pragma("unroll") for (int ks = 0; ks < 2; ++ks)                      \
            af_[mi][ks] = LDfrag(As, bufi, arow, ks);                         \
    }                                                                         \
    _Pragma("unroll") for (int ni = 0; ni < 2; ++ni) {                        \
        int brow = wn * 64 + (nh) * 32 + ni * 16 + lr;                        \
        _Pragma("unroll") for (int ks = 0; ks < 2; ++ks)                      \
            bq_[ni][ks] = LDfrag(Bs, bufi, brow, ks);                         \
    }                                                                         \
    STAGE_STMT;                                                               \
    GATE_STMT;                                                                \
    FENCE; __builtin_amdgcn_s_barrier(); FENCE;                               \
    asm volatile("s_waitcnt lgkmcnt(0)" ::: "memory");                        \
    __builtin_amdgcn_s_setprio(1);                                            \
    _Pragma("unroll") for (int ks = 0; ks < 2; ++ks)                          \
    _Pragma("unroll") for (int mi = 0; mi < 2; ++mi)                          \
    _Pragma("unroll") for (int ni = 0; ni < 2; ++ni)                          \
        acc[(mh) * 2 + mi][(nh) * 2 + ni] =                                   \
            __builtin_amdgcn_mfma_f32_16x16x32_bf16(                          \
                af_[mi][ks], bq_[ni][ks],                                     \
                acc[(mh) * 2 + mi][(nh) * 2 + ni], 0, 0, 0);                  \
    __builtin_amdgcn_s_setprio(0);                                            \
    FENCE; __builtin_amdgcn_s_barrier(); FENCE;                               \
} while (0)

template <int MODE>
__global__ __launch_bounds__(512, 2) void gemm8p(
        const u16* __restrict__ A, const u16* __restrict__ Bt,
        float* __restrict__ fout, u16* __restrict__ q_attn,
        u16* __restrict__ k_attn) {
    const int K = 1024, nt = 16;
    __shared__ u16 As[2][128 * 64];      // 32 KB
    __shared__ u16 Bs[2][256 * 64];      // 64 KB
    int tid = threadIdx.x;
    int w = tid >> 6, lane = tid & 63;
    int m0 = blockIdx.y * 128, n0 = blockIdx.x * 256;
    int wm = w & 1, wn = w >> 1;         // 2M x 4N waves
    int lr = lane & 15, kg = lane >> 4;

    f32x4 acc[4][4] = {};

    // stage one A unit (8 KB = 8 wave-KB): half=0 -> rows {0-31,64-95}
    auto stageA = [&](int buf, int half, int t) {
        int ci = ((w & 3) << 6) + lane + ((w >> 2) << 9) + (half << 8);
        int row = ci >> 3, cg = (ci & 7) ^ (row & 7);
        gl_lds16(A + (size_t)(m0 + row) * K + t * 64 + cg * 8, &As[buf][ci * 8]);
    };
    // stage one B unit (16 KB = 16 wave-KB): half=0 -> rows {s*64+0..31}
    auto stageB = [&](int buf, int half, int t) {
#pragma unroll
        for (int j = 0; j < 2; ++j) {
            int u = w + 8 * j;
            int ci = ((u >> 2) << 9) + ((u & 3) << 6) + lane + (half << 8);
            int row = ci >> 3, cg = (ci & 7) ^ (row & 7);
            gl_lds16(Bt + (size_t)(n0 + row) * K + t * 64 + cg * 8, &Bs[buf][ci * 8]);
        }
    };

    // prologue: full tile 0 (issue order SA0,SB0,SA1,SB1 = 1+2+1+2 loads)
    stageA(0, 0, 0);
    stageB(0, 0, 0);
    stageA(0, 1, 0);
    stageB(0, 1, 0);
    WAITV(3);                            // SA0+SB0 of tile 0 resident
    FENCE; __builtin_amdgcn_s_barrier(); FENCE;

    for (int t = 0; t < nt - 1; ++t) {
        int cur = t & 1, nxt = cur ^ 1;
        PH(cur, 0, 0, stageA(nxt, 0, t + 1), WAITV(3));
        PH(cur, 1, 0, stageB(nxt, 0, t + 1), WAITV(3));
        PH(cur, 1, 1, stageA(nxt, 1, t + 1), ((void)0));
        PH(cur, 0, 1, stageB(nxt, 1, t + 1), WAITV(3));
    }
    // last tile (buf 1): no staging; drain 2 -> 0
    PH(1, 0, 0, ((void)0), WAITV(2));
    PH(1, 1, 0, ((void)0), WAITV(0));
    PH(1, 1, 1, ((void)0), ((void)0));
    PH(1, 0, 1, ((void)0), ((void)0));

    if (MODE == 1) {
#pragma unroll
        for (int am = 0; am < 4; ++am) {
            int mbase = m0 + wm * 64 + am * 16 + kg * 4;
#pragma unroll
            for (int bn = 0; bn < 4; ++bn) {
                int col = n0 + wn * 64 + bn * 16 + lr;
#pragma unroll
                for (int r = 0; r < 4; ++r)
                    fout[(size_t)(mbase + r) * 1024 + col] = acc[am][bn][r];
            }
        }
    } else {
        int matId = n0 >> 10;                  // 0=q 1=k 2=v
        int ncol0 = (n0 & 1023) + wn * 64;
#pragma unroll
        for (int am = 0; am < 4; ++am) {
            int mbase = m0 + wm * 64 + am * 16 + kg * 4;
#pragma unroll
            for (int bn = 0; bn < 4; ++bn) {
                int col = ncol0 + bn * 16 + lr;
#pragma unroll
                for (int r = 0; r < 4; ++r) {
                    int mm = mbase + r;
                    float v = acc[am][bn][r];
                    size_t idx = (size_t)mm * 1024 + col;
                    if (matId == 0) {
                        q_attn[idx] = f2bf(v * QSCALE);   // 1/sqrt(64)*log2e
                    } else if (matId == 1) {
                        fout[(size_t)BSD + idx] = v;
                        k_attn[idx] = f2bf(v);
                    } else {
                        fout[(size_t)2 * BSD + idx] = v;
                    }
                }
            }
        }
    }
}

// ---------------------------------------------------------------------------
// 3. Dedicated projections, fp32 partials over d-chunks (round-0 exact).
// ---------------------------------------------------------------------------
__global__ __launch_bounds__(256) void ded_partial(
        const float* __restrict__ x, const float* __restrict__ Wq,
        const float* __restrict__ Wk, const float* __restrict__ Wv,
        float* __restrict__ part) {
    int dc = blockIdx.x, n = blockIdx.y, mat = blockIdx.z;
    const float* W = ((mat == 0) ? Wq : (mat == 1) ? Wk : Wv) +
                     (size_t)n * 1024 * 1024;
    __shared__ float xs[8 * 128];
    int t = threadIdx.x;
    for (int i = t; i < 1024; i += 256) {
        int b = i >> 7, d = i & 127;
        xs[i] = x[((size_t)b * 1024 + n) * 1024 + dc * 128 + d];
    }
    __syncthreads();
    int o0 = t * 4;
    float4 acc[8];
#pragma unroll
    for (int b = 0; b < 8; ++b) acc[b] = make_float4(0.f, 0.f, 0.f, 0.f);
    for (int d = 0; d < 128; d += 4) {
        float4 w0 = *(const float4*)&W[(size_t)(dc * 128 + d + 0) * 1024 + o0];
        float4 w1 = *(const float4*)&W[(size_t)(dc * 128 + d + 1) * 1024 + o0];
        float4 w2 = *(const float4*)&W[(size_t)(dc * 128 + d + 2) * 1024 + o0];
        float4 w3 = *(const float4*)&W[(size_t)(dc * 128 + d + 3) * 1024 + o0];
#pragma unroll
        for (int b = 0; b < 8; ++b) {
            float x0 = xs[b * 128 + d], x1 = xs[b * 128 + d + 1];
            float x2 = xs[b * 128 + d + 2], x3 = xs[b * 128 + d + 3];
            acc[b].x += x0 * w0.x + x1 * w1.x + x2 * w2.x + x3 * w3.x;
            acc[b].y += x0 * w0.y + x1 * w1.y + x2 * w2.y + x3 * w3.y;
            acc[b].z += x0 * w0.z + x1 * w1.z + x2 * w2.z + x3 * w3.z;
            acc[b].w += x0 * w0.w + x1 * w1.w + x2 * w2.w + x3 * w3.w;
        }
    }
#pragma unroll
    for (int b = 0; b < 8; ++b)
        *(float4*)&part[(size_t)(((mat * 8 + dc) * 8 + b) * 16 + n) * 1024 + o0] = acc[b];
}

// ---------------------------------------------------------------------------
// 4. Fused fixup + vT build (disjoint block families; round-2 exact).
// ---------------------------------------------------------------------------
__global__ __launch_bounds__(256) void fix_vt(
        const float* __restrict__ part, float* __restrict__ d_out,
        u16* __restrict__ q_attn, u16* __restrict__ k_attn,
        const float* __restrict__ vf, u16* __restrict__ vT) {
    __shared__ float t[64][65];
    int bid = blockIdx.x;
    int tid = threadIdx.x;

    if (bid < 384) {
        // ---- ded_fixup
        int mat = bid >> 7, b = (bid >> 4) & 7, n = bid & 15;
        int o0 = tid * 4;
        float v[4] = {0.f, 0.f, 0.f, 0.f};
        for (int dc = 0; dc < 8; ++dc) {
            float4 p = *(const float4*)&part[(size_t)(((mat * 8 + dc) * 8 + b) * 16 + n) * 1024 + o0];
            v[0] += p.x; v[1] += p.y; v[2] += p.z; v[3] += p.w;
        }
#pragma unroll
        for (int j = 0; j < 4; ++j) {
            int col = o0 + j;
            size_t idx = ((size_t)b * 1024 + n) * 1024 + col;
            if (mat == 0) {
                q_attn[idx] = f2bf(v[j] * QSCALE);
            } else if (mat == 1) {
                d_out[(size_t)BSD + idx] = v[j];
                k_attn[idx] = f2bf(v[j]);
            } else {
                d_out[(size_t)2 * BSD + idx] = v[j];
                // vT slot for this (token<16, col): transpose blocks skip it
                int h = col >> 6, hd = col & 63;
                vT[((size_t)((b * 16 + h) * 64 + hd)) * 1024 + n] = f2bf(v[j]);
            }
        }
        return;
    }

    // ---- v_transpose: read v fp32 [B,S,H,HD] (L3-hot), write vT bf16 [B,H,HD,S]
    int id = bid - 384;
    int st = id & 15, h = (id >> 4) & 15, b = id >> 8;
    int cg = tid & 15, sl = tid >> 4;      // 16 hd-groups x 16 s-rows
#pragma unroll
    for (int p = 0; p < 4; ++p) {
        int s = p * 16 + sl;
        float4 v = *(const float4*)&vf[
            ((size_t)(b * 1024 + st * 64 + s)) * 1024 + h * 64 + cg * 4];
        t[cg * 4 + 0][s] = v.x;
        t[cg * 4 + 1][s] = v.y;
        t[cg * 4 + 2][s] = v.z;
        t[cg * 4 + 3][s] = v.w;
    }
    __syncthreads();
    int hd = tid >> 2, sc = (tid & 3) * 16;
    if (st == 0 && sc == 0) return;        // s<16 handled by fixup blocks
    u16* dst = vT + ((size_t)((b * 16 + h) * 64 + hd)) * 1024 + st * 64 + sc;
#pragma unroll
    for (int c = 0; c < 4; ++c) {
        ushort4 o;
        o.x = f2bf(t[hd][sc + c * 4 + 0]);
        o.y = f2bf(t[hd][sc + c * 4 + 1]);
        o.z = f2bf(t[hd][sc + c * 4 + 2]);
        o.w = f2bf(t[hd][sc + c * 4 + 3]);
        *(ushort4*)(dst + c * 4) = o;
    }
}

// ---------------------------------------------------------------------------
// 5. Flash attention, fixed-reference softmax (round-0 exact).
// ---------------------------------------------------------------------------
__global__ __launch_bounds__(256) void attn(
        const u16* __restrict__ q_attn, const u16* __restrict__ k_attn,
        const u16* __restrict__ vT, u16* __restrict__ O) {
    int qt = 7 - blockIdx.x;               // long-pole blocks first
    int h = blockIdx.y, b = blockIdx.z;
    const u16* Qg = q_attn + ((size_t)(b * 1024) + qt * 128) * 1024 + h * 64;
    const u16* Kg = k_attn + ((size_t)(b * 1024)) * 1024 + h * 64;
    const u16* Vg = vT + (size_t)((b * 16 + h) * 64) * 1024;

    __shared__ u16 Qs[128 * 64];
    __shared__ u16 Ks[64 * 64];
    __shared__ u16 Vs[64 * 64];     // V^T tile: [hd][kk]
    __shared__ u16 Ps[128 * 64];    // P: [q][kk], per-wave private rows
    __shared__ float red[4 * 32];   // per-wave l broadcast (epilogue only)

    int tid = threadIdx.x, wave = tid >> 6, lane = tid & 63;
    int lr = lane & 15, kg = lane >> 4;

#pragma unroll
    for (int j = 0; j < 4; ++j) {   // Q: 1024 16B chunks, row stride 1024
        int ci = j * 256 + tid;
        int row = ci >> 3, cg = (ci & 7) ^ (row & 7);
        gl_lds16(Qg + (size_t)row * 1024 + cg * 8, Qs + ci * 8);
    }

    float l_acc[2] = {0.f, 0.f};
    f32x4 oacc[2][4] = {};

    int nkt = 2 * qt + 2;
    for (int kt = 0; kt < nkt; ++kt) {
        __syncthreads();            // prev-iter LDS reads done
#pragma unroll
        for (int j = 0; j < 2; ++j) {   // K,V tiles: 512 chunks each
            int ci = j * 256 + tid;
            int row = ci >> 3, cg = (ci & 7) ^ (row & 7);
            gl_lds16(Kg + (size_t)(kt * 64 + row) * 1024 + cg * 8, Ks + ci * 8);
            gl_lds16(Vg + (size_t)row * 1024 + kt * 64 + cg * 8, Vs + ci * 8);
        }
        __syncthreads();            // drains vmcnt (incl. Q on kt=0)

        // fully-masked wave on the top diagonal tile: contributes nothing
        bool wactive = (qt * 128 + wave * 32 + 31) >= kt * 64;
        if (wactive) {
            // S^T = K * Q^T : m=kk(64), n=q(32 per wave), k=hd
            f32x4 sacc[4][2] = {};
#pragma unroll
            for (int ks = 0; ks < 2; ++ks) {
                bf16x8 af[4], bq[2];
#pragma unroll
                for (int mi = 0; mi < 4; ++mi) {
                    int row = mi * 16 + lr;
                    af[mi] = __builtin_bit_cast(bf16x8,
                        *(const u16x8*)&Ks[row * 64 + (((ks * 4 + kg) ^ (row & 7)) * 8)]);
                }
#pragma unroll
                for (int nj = 0; nj < 2; ++nj) {
                    int qr = wave * 32 + nj * 16 + lr;
                    bq[nj] = __builtin_bit_cast(bf16x8,
                        *(const u16x8*)&Qs[qr * 64 + (((ks * 4 + kg) ^ (qr & 7)) * 8)]);
                }
#pragma unroll
                for (int mi = 0; mi < 4; ++mi)
#pragma unroll
                    for (int nj = 0; nj < 2; ++nj)
                        sacc[mi][nj] = __builtin_amdgcn_mfma_f32_16x16x32_bf16(
                            af[mi], bq[nj], sacc[mi][nj], 0, 0, 0);
            }

            if (kt >= 2 * qt) {         // diagonal tiles: causal mask
#pragma unroll
                for (int mi = 0; mi < 4; ++mi)
#pragma unroll
                    for (int nj = 0; nj < 2; ++nj)
#pragma unroll
                        for (int r = 0; r < 4; ++r) {
                            int kk_g = kt * 64 + mi * 16 + kg * 4 + r;
                            int q_g  = qt * 128 + wave * 32 + nj * 16 + lr;
                            if (kk_g > q_g) sacc[mi][nj][r] = -1e30f;
                        }
            }

            // p = exp2(s); accumulate row-sums per-lane; pack via v_perm
#pragma unroll
            for (int nj = 0; nj < 2; ++nj) {
                int q = wave * 32 + nj * 16 + lr;
                float lsum = 0.f;
#pragma unroll
                for (int mi = 0; mi < 4; ++mi) {
                    float p0 = __builtin_amdgcn_exp2f(sacc[mi][nj][0]);
                    float p1 = __builtin_amdgcn_exp2f(sacc[mi][nj][1]);
                    float p2 = __builtin_amdgcn_exp2f(sacc[mi][nj][2]);
                    float p3 = __builtin_amdgcn_exp2f(sacc[mi][nj][3]);
                    lsum += (p0 + p1) + (p2 + p3);
                    int kkc = mi * 2 + (kg >> 1);      // kk chunk = kk>>3
                    int off = q * 64 + ((kkc ^ (q & 7)) * 8) + (kg & 1) * 4;
                    uint2 w2;
                    w2.x = pack_bf2(p0, p1);
                    w2.y = pack_bf2(p2, p3);
                    *(uint2*)&Ps[off] = w2;
                }
                l_acc[nj] += lsum;
            }

            // PV: O += P * V^T
#pragma unroll
            for (int ks = 0; ks < 2; ++ks) {
                bf16x8 ap[2], bv[4];
#pragma unroll
                for (int mi = 0; mi < 2; ++mi) {
                    int q = wave * 32 + mi * 16 + lr;
                    ap[mi] = __builtin_bit_cast(bf16x8,
                        *(const u16x8*)&Ps[q * 64 + (((ks * 4 + kg) ^ (q & 7)) * 8)]);
                }
#pragma unroll
                for (int nj = 0; nj < 4; ++nj) {
                    int hd = nj * 16 + lr;
                    bv[nj] = __builtin_bit_cast(bf16x8,
                        *(const u16x8*)&Vs[hd * 64 + (((ks * 4 + kg) ^ (hd & 7)) * 8)]);
                }
#pragma unroll
                for (int mi = 0; mi < 2; ++mi)
#pragma unroll
                    for (int nj = 0; nj < 4; ++nj)
                        oacc[mi][nj] = __builtin_amdgcn_mfma_f32_16x16x32_bf16(
                            ap[mi], bv[nj], oacc[mi][nj], 0, 0, 0);
            }
        }
    }

    // epilogue: reduce l across kg-lanes, O /= l, write bf16 [B,S,H*HD]
#pragma unroll
    for (int nj = 0; nj < 2; ++nj) {
        float l = l_acc[nj];
        l += __shfl_xor(l, 16);
        l += __shfl_xor(l, 32);
        if (kg == 0) red[wave * 32 + nj * 16 + lr] = l;
    }
#pragma unroll
    for (int mi = 0; mi < 2; ++mi) {
        f32x4 lv = *(f32x4*)&red[wave * 32 + mi * 16 + kg * 4];
        f32x4 rv;
#pragma unroll
        for (int r = 0; r < 4; ++r) rv[r] = __builtin_amdgcn_rcpf(lv[r]);
#pragma unroll
        for (int nj = 0; nj < 4; ++nj)
#pragma unroll
            for (int r = 0; r < 4; ++r) {
                int q_local = wave * 32 + mi * 16 + kg * 4 + r;
                size_t row = (size_t)b * 1024 + qt * 128 + q_local;
                O[row * 1024 + h * 64 + nj * 16 + lr] =
                    f2bf(oacc[mi][nj][r] * rv[r]);
            }
    }
}

// ---------------------------------------------------------------------------
extern "C" void kernel_launch(void* const* d_in, const int* in_sizes, int n_in,
                              void* d_out, int out_size, void* d_ws, size_t ws_size,
                              hipStream_t stream) {
    const float* x   = (const float*)d_in[0];
    const float* Wq  = (const float*)d_in[1];
    const float* Wk  = (const float*)d_in[2];
    const float* Wv  = (const float*)d_in[3];
    const float* Wqd = (const float*)d_in[4];
    const float* Wkd = (const float*)d_in[5];
    const float* Wvd = (const float*)d_in[6];
    const float* Wo  = (const float*)d_in[7];
    float* out = (float*)d_out;

    char* ws = (char*)d_ws;
    u16*   WTcat  = (u16*)(ws);                    //  6 MB  [3072][1024] bf16
    u16*   WoT    = (u16*)(ws + 6291456);          //  2 MB
    u16*   xb     = (u16*)(ws + 8388608);          // 16 MB  [8192][1024] bf16
    u16*   q_attn = (u16*)(ws + 25165824);         // 16 MB  [B,S,D] bf16 (prescaled)
    u16*   k_attn = (u16*)(ws + 41943040);         // 16 MB  [B,S,D] bf16
    u16*   vT     = (u16*)(ws + 58720256);         // 16 MB  [B,H,64,S]
    u16*   Ow     = (u16*)(ws + 75497472);         // 16 MB  [8192][1024]
    float* part   = (float*)(ws + 92274688);       // 12 MB  partials

    cvt_fused<<<dim3(32, 32, 12), 256, 0, stream>>>(
        Wq, Wk, Wv, Wo, WTcat, WoT, (const float4*)x, xb);
    gemm8p<0><<<dim3(12, 64), 512, 0, stream>>>(xb, WTcat, out, q_attn, k_attn);
    ded_partial<<<dim3(8, 16, 3), 256, 0, stream>>>(x, Wqd, Wkd, Wvd, part);
    fix_vt<<<dim3(2432), 256, 0, stream>>>(
        part, out, q_attn, k_attn, out + (size_t)2 * BSD, vT);
    attn<<<dim3(8, 16, 8), 256, 0, stream>>>(q_attn, k_attn, vT, Ow);
    gemm8p<1><<<dim3(4, 64), 512, 0, stream>>>(Ow, WoT, out, nullptr, nullptr);
}

// Round 4
// 459.027 us; speedup vs baseline: 1.0332x; 1.0332x over previous
//
#include <hip/hip_runtime.h>
#include <cstdint>

// ---------------------------------------------------------------------------
// MixedMHA: x[8,1024,1024] -> (output, k, v), causal MHA with per-token
// dedicated QKV weights for the first 16 tokens.
// Round 4: MODE0 GEMM restructured after round-3 post-mortem (8 MFMA/barrier
// was too small a quantum). New gemm_qkv: BM=128 BN=256 BK=64, 8 waves
// (2Mx4N, per-wave C 64x64), 2 phases per K-tile (ks-split, 16 MFMA each),
// ONE barrier per K-tile, all 6 stage loads of tile t+1 front-loaded at
// phase 1 of tile t, single vmcnt(0) gate ~600cyc downstream of issue.
// Grid 12x64 = 768 blocks = 3 exact CU-rounds. Accumulation order identical
// to round 2 (bit-identical results).
// MODE1 keeps round-3 gemm8p (inferred ~17us vs 30us for gemm128<1>).
// Everything else round-2/3 proven code.
// ---------------------------------------------------------------------------

typedef unsigned short u16;
typedef __attribute__((ext_vector_type(8)))  __bf16 bf16x8;
typedef __attribute__((ext_vector_type(8)))  u16    u16x8;
typedef __attribute__((ext_vector_type(4)))  float  f32x4;

#define BSD   (8u * 1024u * 1024u)      // one [B,S,D] section in d_out
#define QSCALE 0.18033688011112042f     // 0.125 * log2(e): softmax in exp2 units

__device__ __forceinline__ u16 f2bf(float f) {
    unsigned u = __builtin_bit_cast(unsigned, f);
    u += 0x7fffu + ((u >> 16) & 1u);            // RNE
    return (u16)(u >> 16);
}

// pack hi16(p1):hi16(p0) in one v_perm_b32 (bf16 truncation)
__device__ __forceinline__ unsigned pack_bf2(float p0, float p1) {
    return __builtin_amdgcn_perm(__builtin_bit_cast(unsigned, p1),
                                 __builtin_bit_cast(unsigned, p0), 0x07060302u);
}

__device__ __forceinline__ void gl_lds16(const void* g, void* l) {
    __builtin_amdgcn_global_load_lds(
        (const __attribute__((address_space(1))) unsigned*)g,
        (__attribute__((address_space(3))) unsigned*)l, 16, 0, 0);
}

#define FENCE asm volatile("" ::: "memory")
#define WAITV(n) asm volatile("s_waitcnt vmcnt(" #n ")" ::: "memory")

// ---------------------------------------------------------------------------
// 1. Fused converts (independent block families, no shared state).
// ---------------------------------------------------------------------------
__global__ __launch_bounds__(256) void cvt_fused(
        const float* __restrict__ Wq, const float* __restrict__ Wk,
        const float* __restrict__ Wv, const float* __restrict__ Wo,
        u16* __restrict__ WTcat, u16* __restrict__ WoT,
        const float4* __restrict__ x, u16* __restrict__ xb) {
    __shared__ float t[32][33];
    int z = blockIdx.z;
    if (z < 4) {
        const float* src = (z == 0) ? Wq : (z == 1) ? Wk : (z == 2) ? Wv : Wo;
        u16* dst = (z < 3) ? (WTcat + (size_t)z * 1024 * 1024) : WoT;
        int k0 = blockIdx.x * 32, n0 = blockIdx.y * 32;
        int xx = threadIdx.x & 31, yy = threadIdx.x >> 5;   // 32 x 8
#pragma unroll
        for (int i = 0; i < 4; ++i)
            t[yy + 8 * i][xx] = src[(size_t)(k0 + yy + 8 * i) * 1024 + n0 + xx];
        __syncthreads();
#pragma unroll
        for (int i = 0; i < 4; ++i)
            dst[(size_t)(n0 + yy + 8 * i) * 1024 + k0 + xx] = f2bf(t[xx][yy + 8 * i]);
    } else {
        int lb = (z - 4) * 1024 + blockIdx.y * 32 + blockIdx.x;  // 8192 blocks
        int i = lb * 256 + threadIdx.x;                          // 2M float4
        float4 v = x[i];
        ushort4 o;
        o.x = f2bf(v.x); o.y = f2bf(v.y); o.z = f2bf(v.z); o.w = f2bf(v.w);
        ((ushort4*)xb)[i] = o;
    }
}

// ---------------------------------------------------------------------------
// 2. gemm_qkv: C = A[8192,1024] * Bt[3072,1024]^T with fused QKV epilogue.
// BM=128 BN=256 BK=64, 8 waves (wm=w&1, wn=w>>3? no: wn=w>>1 in 0..3),
// per-wave C = 64x64 (acc f32x4[4][4]).
// Schedule per K-tile t (bufs: tile t in buf t&1):
//   phase ks=0: 8 ds_read_b128 (A 4 + B 4) -> stage ALL of tile t+1 into
//               buf^1 (6 gl_lds) -> 16 MFMA
//   phase ks=1: 8 ds_read_b128 -> 16 MFMA -> WAITV(0) -> barrier
// Safety: stage into buf^1 at tile t is ordered after the end-of-(t-1)
// barrier, and every wave's reads of buf^1 (tile t-1) completed before its
// own MFMA (compiler lgkmcnt) which precedes that barrier -> no WAR.
// Residency of tile t for reads: end-of-(t-1) WAITV(0)+barrier.
// Gate distance: 6 loads issued at phase1, gated after ~32 MFMA + 16 reads.
// ---------------------------------------------------------------------------
__global__ __launch_bounds__(512, 2) void gemm_qkv(
        const u16* __restrict__ A, const u16* __restrict__ Bt,
        float* __restrict__ fout, u16* __restrict__ q_attn,
        u16* __restrict__ k_attn) {
    const int K = 1024, NT = 16;
    __shared__ u16 As[2][128 * 64];      // 32 KB
    __shared__ u16 Bs[2][256 * 64];      // 64 KB
    int tid = threadIdx.x;
    int w = tid >> 6, lane = tid & 63;
    int m0 = blockIdx.y * 128, n0 = blockIdx.x * 256;
    int wm = w & 1, wn = w >> 1;         // 2M x 4N waves
    int lr = lane & 15, kg = lane >> 4;

    f32x4 acc[4][4] = {};

    // stage full tile t into buf: A 2 sweeps + B 4 sweeps (6 gl_lds/thread)
    auto stageAll = [&](int buf, int t) {
#pragma unroll
        for (int s = 0; s < 2; ++s) {
            int ci = s * 512 + tid;
            int row = ci >> 3, cg = (ci & 7) ^ (row & 7);
            gl_lds16(A + (size_t)(m0 + row) * K + t * 64 + cg * 8, &As[buf][ci * 8]);
        }
#pragma unroll
        for (int s = 0; s < 4; ++s) {
            int ci = s * 512 + tid;
            int row = ci >> 3, cg = (ci & 7) ^ (row & 7);
            gl_lds16(Bt + (size_t)(n0 + row) * K + t * 64 + cg * 8, &Bs[buf][ci * 8]);
        }
    };

    stageAll(0, 0);
    WAITV(0);
    FENCE; __builtin_amdgcn_s_barrier(); FENCE;

    for (int t = 0; t < NT; ++t) {
        int cur = t & 1, nxt = cur ^ 1;
        // ---- phase ks = 0
        {
            bf16x8 af[4], bf[4];
#pragma unroll
            for (int mi = 0; mi < 4; ++mi) {
                int row = wm * 64 + mi * 16 + lr;
                af[mi] = __builtin_bit_cast(bf16x8,
                    *(const u16x8*)&As[cur][row * 64 + ((kg ^ (row & 7)) * 8)]);
            }
#pragma unroll
            for (int ni = 0; ni < 4; ++ni) {
                int row = wn * 64 + ni * 16 + lr;
                bf[ni] = __builtin_bit_cast(bf16x8,
                    *(const u16x8*)&Bs[cur][row * 64 + ((kg ^ (row & 7)) * 8)]);
            }
            if (t < NT - 1) stageAll(nxt, t + 1);
            __builtin_amdgcn_s_setprio(1);
#pragma unroll
            for (int mi = 0; mi < 4; ++mi)
#pragma unroll
                for (int ni = 0; ni < 4; ++ni)
                    acc[mi][ni] = __builtin_amdgcn_mfma_f32_16x16x32_bf16(
                        af[mi], bf[ni], acc[mi][ni], 0, 0, 0);
            __builtin_amdgcn_s_setprio(0);
        }
        // ---- phase ks = 1
        {
            bf16x8 af[4], bf[4];
#pragma unroll
            for (int mi = 0; mi < 4; ++mi) {
                int row = wm * 64 + mi * 16 + lr;
                af[mi] = __builtin_bit_cast(bf16x8,
                    *(const u16x8*)&As[cur][row * 64 + (((4 + kg) ^ (row & 7)) * 8)]);
            }
#pragma unroll
            for (int ni = 0; ni < 4; ++ni) {
                int row = wn * 64 + ni * 16 + lr;
                bf[ni] = __builtin_bit_cast(bf16x8,
                    *(const u16x8*)&Bs[cur][row * 64 + (((4 + kg) ^ (row & 7)) * 8)]);
            }
            __builtin_amdgcn_s_setprio(1);
#pragma unroll
            for (int mi = 0; mi < 4; ++mi)
#pragma unroll
                for (int ni = 0; ni < 4; ++ni)
                    acc[mi][ni] = __builtin_amdgcn_mfma_f32_16x16x32_bf16(
                        af[mi], bf[ni], acc[mi][ni], 0, 0, 0);
            __builtin_amdgcn_s_setprio(0);
        }
        if (t < NT - 1) {
            WAITV(0);                    // tile t+1 resident (issued 1 phase ago)
            FENCE; __builtin_amdgcn_s_barrier(); FENCE;
        }
    }

    int matId = n0 >> 10;                  // 0=q 1=k 2=v
    int ncol0 = (n0 & 1023) + wn * 64;
#pragma unroll
    for (int am = 0; am < 4; ++am) {
        int mbase = m0 + wm * 64 + am * 16 + kg * 4;
#pragma unroll
        for (int bn = 0; bn < 4; ++bn) {
            int col = ncol0 + bn * 16 + lr;
#pragma unroll
            for (int r = 0; r < 4; ++r) {
                int mm = mbase + r;
                float v = acc[am][bn][r];
                size_t idx = (size_t)mm * 1024 + col;
                if (matId == 0) {
                    q_attn[idx] = f2bf(v * QSCALE);   // 1/sqrt(64)*log2e
                } else if (matId == 1) {
                    fout[(size_t)BSD + idx] = v;
                    k_attn[idx] = f2bf(v);
                } else {
                    fout[(size_t)2 * BSD + idx] = v;
                }
            }
        }
    }
}

// ---------------------------------------------------------------------------
// 6. gemm8p MODE1 (round-3 exact; kept — inferred faster than gemm128<1>).
// BM=128 BN=256 BK=64, 8 waves, 4 quadrant phases per K-tile.
// ---------------------------------------------------------------------------
#define LDfrag(BUF, bufi, row, ks)                                            \
    __builtin_bit_cast(bf16x8, *(const u16x8*)&BUF[bufi]                      \
        [(row) * 64 + ((((ks) * 4 + kg) ^ ((row) & 7)) * 8)])

#define PH(bufi, mh, nh, STAGE_STMT, GATE_STMT) do {                          \
    bf16x8 af_[2][2], bq_[2][2];                                              \
    _Pragma("unroll") for (int mi = 0; mi < 2; ++mi) {                        \
        int arow = wm * 64 + (mh) * 32 + mi * 16 + lr;                        \
        _Pragma("unroll") for (int ks = 0; ks < 2; ++ks)                      \
            af_[mi][ks] = LDfrag(As, bufi, arow, ks);                         \
    }                                                                         \
    _Pragma("unroll") for (int ni = 0; ni < 2; ++ni) {                        \
        int brow = wn * 64 + (nh) * 32 + ni * 16 + lr;                        \
        _Pragma("unroll") for (int ks = 0; ks < 2; ++ks)                      \
            bq_[ni][ks] = LDfrag(Bs, bufi, brow, ks);                         \
    }                                                                         \
    STAGE_STMT;                                                               \
    GATE_STMT;                                                                \
    FENCE; __builtin_amdgcn_s_barrier(); FENCE;                               \
    asm volatile("s_waitcnt lgkmcnt(0)" ::: "memory");                        \
    __builtin_amdgcn_s_setprio(1);                                            \
    _Pragma("unroll") for (int ks = 0; ks < 2; ++ks)                          \
    _Pragma("unroll") for (int mi = 0; mi < 2; ++mi)                          \
    _Pragma("unroll") for (int ni = 0; ni < 2; ++ni)                          \
        acc[(mh) * 2 + mi][(nh) * 2 + ni] =                                   \
            __builtin_amdgcn_mfma_f32_16x16x32_bf16(                          \
                af_[mi][ks], bq_[ni][ks],                                     \
                acc[(mh) * 2 + mi][(nh) * 2 + ni], 0, 0, 0);                  \
    __builtin_amdgcn_s_setprio(0);                                            \
    FENCE; __builtin_amdgcn_s_barrier(); FENCE;                               \
} while (0)

__global__ __launch_bounds__(512, 2) void gemm8p_wo(
        const u16* __restrict__ A, const u16* __restrict__ Bt,
        float* __restrict__ fout) {
    const int K = 1024, nt = 16;
    __shared__ u16 As[2][128 * 64];      // 32 KB
    __shared__ u16 Bs[2][256 * 64];      // 64 KB
    int tid = threadIdx.x;
    int w = tid >> 6, lane = tid & 63;
    int m0 = blockIdx.y * 128, n0 = blockIdx.x * 256;
    int wm = w & 1, wn = w >> 1;         // 2M x 4N waves
    int lr = lane & 15, kg = lane >> 4;

    f32x4 acc[4][4] = {};

    auto stageA = [&](int buf, int half, int t) {
        int ci = ((w & 3) << 6) + lane + ((w >> 2) << 9) + (half << 8);
        int row = ci >> 3, cg = (ci & 7) ^ (row & 7);
        gl_lds16(A + (size_t)(m0 + row) * K + t * 64 + cg * 8, &As[buf][ci * 8]);
    };
    auto stageB = [&](int buf, int half, int t) {
#pragma unroll
        for (int j = 0; j < 2; ++j) {
            int u = w + 8 * j;
            int ci = ((u >> 2) << 9) + ((u & 3) << 6) + lane + (half << 8);
            int row = ci >> 3, cg = (ci & 7) ^ (row & 7);
            gl_lds16(Bt + (size_t)(n0 + row) * K + t * 64 + cg * 8, &Bs[buf][ci * 8]);
        }
    };

    stageA(0, 0, 0);
    stageB(0, 0, 0);
    stageA(0, 1, 0);
    stageB(0, 1, 0);
    WAITV(3);
    FENCE; __builtin_amdgcn_s_barrier(); FENCE;

    for (int t = 0; t < nt - 1; ++t) {
        int cur = t & 1, nxt = cur ^ 1;
        PH(cur, 0, 0, stageA(nxt, 0, t + 1), WAITV(3));
        PH(cur, 1, 0, stageB(nxt, 0, t + 1), WAITV(3));
        PH(cur, 1, 1, stageA(nxt, 1, t + 1), ((void)0));
        PH(cur, 0, 1, stageB(nxt, 1, t + 1), WAITV(3));
    }
    PH(1, 0, 0, ((void)0), WAITV(2));
    PH(1, 1, 0, ((void)0), WAITV(0));
    PH(1, 1, 1, ((void)0), ((void)0));
    PH(1, 0, 1, ((void)0), ((void)0));

#pragma unroll
    for (int am = 0; am < 4; ++am) {
        int mbase = m0 + wm * 64 + am * 16 + kg * 4;
#pragma unroll
        for (int bn = 0; bn < 4; ++bn) {
            int col = n0 + wn * 64 + bn * 16 + lr;
#pragma unroll
            for (int r = 0; r < 4; ++r)
                fout[(size_t)(mbase + r) * 1024 + col] = acc[am][bn][r];
        }
    }
}

// ---------------------------------------------------------------------------
// 3. Dedicated projections, fp32 partials over d-chunks (round-0 exact).
// ---------------------------------------------------------------------------
__global__ __launch_bounds__(256) void ded_partial(
        const float* __restrict__ x, const float* __restrict__ Wq,
        const float* __restrict__ Wk, const float* __restrict__ Wv,
        float* __restrict__ part) {
    int dc = blockIdx.x, n = blockIdx.y, mat = blockIdx.z;
    const float* W = ((mat == 0) ? Wq : (mat == 1) ? Wk : Wv) +
                     (size_t)n * 1024 * 1024;
    __shared__ float xs[8 * 128];
    int t = threadIdx.x;
    for (int i = t; i < 1024; i += 256) {
        int b = i >> 7, d = i & 127;
        xs[i] = x[((size_t)b * 1024 + n) * 1024 + dc * 128 + d];
    }
    __syncthreads();
    int o0 = t * 4;
    float4 acc[8];
#pragma unroll
    for (int b = 0; b < 8; ++b) acc[b] = make_float4(0.f, 0.f, 0.f, 0.f);
    for (int d = 0; d < 128; d += 4) {
        float4 w0 = *(const float4*)&W[(size_t)(dc * 128 + d + 0) * 1024 + o0];
        float4 w1 = *(const float4*)&W[(size_t)(dc * 128 + d + 1) * 1024 + o0];
        float4 w2 = *(const float4*)&W[(size_t)(dc * 128 + d + 2) * 1024 + o0];
        float4 w3 = *(const float4*)&W[(size_t)(dc * 128 + d + 3) * 1024 + o0];
#pragma unroll
        for (int b = 0; b < 8; ++b) {
            float x0 = xs[b * 128 + d], x1 = xs[b * 128 + d + 1];
            float x2 = xs[b * 128 + d + 2], x3 = xs[b * 128 + d + 3];
            acc[b].x += x0 * w0.x + x1 * w1.x + x2 * w2.x + x3 * w3.x;
            acc[b].y += x0 * w0.y + x1 * w1.y + x2 * w2.y + x3 * w3.y;
            acc[b].z += x0 * w0.z + x1 * w1.z + x2 * w2.z + x3 * w3.z;
            acc[b].w += x0 * w0.w + x1 * w1.w + x2 * w2.w + x3 * w3.w;
        }
    }
#pragma unroll
    for (int b = 0; b < 8; ++b)
        *(float4*)&part[(size_t)(((mat * 8 + dc) * 8 + b) * 16 + n) * 1024 + o0] = acc[b];
}

// ---------------------------------------------------------------------------
// 4. Fused fixup + vT build (disjoint block families; round-2 exact).
// ---------------------------------------------------------------------------
__global__ __launch_bounds__(256) void fix_vt(
        const float* __restrict__ part, float* __restrict__ d_out,
        u16* __restrict__ q_attn, u16* __restrict__ k_attn,
        const float* __restrict__ vf, u16* __restrict__ vT) {
    __shared__ float t[64][65];
    int bid = blockIdx.x;
    int tid = threadIdx.x;

    if (bid < 384) {
        // ---- ded_fixup
        int mat = bid >> 7, b = (bid >> 4) & 7, n = bid & 15;
        int o0 = tid * 4;
        float v[4] = {0.f, 0.f, 0.f, 0.f};
        for (int dc = 0; dc < 8; ++dc) {
            float4 p = *(const float4*)&part[(size_t)(((mat * 8 + dc) * 8 + b) * 16 + n) * 1024 + o0];
            v[0] += p.x; v[1] += p.y; v[2] += p.z; v[3] += p.w;
        }
#pragma unroll
        for (int j = 0; j < 4; ++j) {
            int col = o0 + j;
            size_t idx = ((size_t)b * 1024 + n) * 1024 + col;
            if (mat == 0) {
                q_attn[idx] = f2bf(v[j] * QSCALE);
            } else if (mat == 1) {
                d_out[(size_t)BSD + idx] = v[j];
                k_attn[idx] = f2bf(v[j]);
            } else {
                d_out[(size_t)2 * BSD + idx] = v[j];
                // vT slot for this (token<16, col): transpose blocks skip it
                int h = col >> 6, hd = col & 63;
                vT[((size_t)((b * 16 + h) * 64 + hd)) * 1024 + n] = f2bf(v[j]);
            }
        }
        return;
    }

    // ---- v_transpose: read v fp32 [B,S,H,HD] (L3-hot), write vT bf16 [B,H,HD,S]
    int id = bid - 384;
    int st = id & 15, h = (id >> 4) & 15, b = id >> 8;
    int cg = tid & 15, sl = tid >> 4;      // 16 hd-groups x 16 s-rows
#pragma unroll
    for (int p = 0; p < 4; ++p) {
        int s = p * 16 + sl;
        float4 v = *(const float4*)&vf[
            ((size_t)(b * 1024 + st * 64 + s)) * 1024 + h * 64 + cg * 4];
        t[cg * 4 + 0][s] = v.x;
        t[cg * 4 + 1][s] = v.y;
        t[cg * 4 + 2][s] = v.z;
        t[cg * 4 + 3][s] = v.w;
    }
    __syncthreads();
    int hd = tid >> 2, sc = (tid & 3) * 16;
    if (st == 0 && sc == 0) return;        // s<16 handled by fixup blocks
    u16* dst = vT + ((size_t)((b * 16 + h) * 64 + hd)) * 1024 + st * 64 + sc;
#pragma unroll
    for (int c = 0; c < 4; ++c) {
        ushort4 o;
        o.x = f2bf(t[hd][sc + c * 4 + 0]);
        o.y = f2bf(t[hd][sc + c * 4 + 1]);
        o.z = f2bf(t[hd][sc + c * 4 + 2]);
        o.w = f2bf(t[hd][sc + c * 4 + 3]);
        *(ushort4*)(dst + c * 4) = o;
    }
}

// ---------------------------------------------------------------------------
// 5. Flash attention, fixed-reference softmax (round-0 exact).
// ---------------------------------------------------------------------------
__global__ __launch_bounds__(256) void attn(
        const u16* __restrict__ q_attn, const u16* __restrict__ k_attn,
        const u16* __restrict__ vT, u16* __restrict__ O) {
    int qt = 7 - blockIdx.x;               // long-pole blocks first
    int h = blockIdx.y, b = blockIdx.z;
    const u16* Qg = q_attn + ((size_t)(b * 1024) + qt * 128) * 1024 + h * 64;
    const u16* Kg = k_attn + ((size_t)(b * 1024)) * 1024 + h * 64;
    const u16* Vg = vT + (size_t)((b * 16 + h) * 64) * 1024;

    __shared__ u16 Qs[128 * 64];
    __shared__ u16 Ks[64 * 64];
    __shared__ u16 Vs[64 * 64];     // V^T tile: [hd][kk]
    __shared__ u16 Ps[128 * 64];    // P: [q][kk], per-wave private rows
    __shared__ float red[4 * 32];   // per-wave l broadcast (epilogue only)

    int tid = threadIdx.x, wave = tid >> 6, lane = tid & 63;
    int lr = lane & 15, kg = lane >> 4;

#pragma unroll
    for (int j = 0; j < 4; ++j) {   // Q: 1024 16B chunks, row stride 1024
        int ci = j * 256 + tid;
        int row = ci >> 3, cg = (ci & 7) ^ (row & 7);
        gl_lds16(Qg + (size_t)row * 1024 + cg * 8, Qs + ci * 8);
    }

    float l_acc[2] = {0.f, 0.f};
    f32x4 oacc[2][4] = {};

    int nkt = 2 * qt + 2;
    for (int kt = 0; kt < nkt; ++kt) {
        __syncthreads();            // prev-iter LDS reads done
#pragma unroll
        for (int j = 0; j < 2; ++j) {   // K,V tiles: 512 chunks each
            int ci = j * 256 + tid;
            int row = ci >> 3, cg = (ci & 7) ^ (row & 7);
            gl_lds16(Kg + (size_t)(kt * 64 + row) * 1024 + cg * 8, Ks + ci * 8);
            gl_lds16(Vg + (size_t)row * 1024 + kt * 64 + cg * 8, Vs + ci * 8);
        }
        __syncthreads();            // drains vmcnt (incl. Q on kt=0)

        // fully-masked wave on the top diagonal tile: contributes nothing
        bool wactive = (qt * 128 + wave * 32 + 31) >= kt * 64;
        if (wactive) {
            // S^T = K * Q^T : m=kk(64), n=q(32 per wave), k=hd
            f32x4 sacc[4][2] = {};
#pragma unroll
            for (int ks = 0; ks < 2; ++ks) {
                bf16x8 af[4], bq[2];
#pragma unroll
                for (int mi = 0; mi < 4; ++mi) {
                    int row = mi * 16 + lr;
                    af[mi] = __builtin_bit_cast(bf16x8,
                        *(const u16x8*)&Ks[row * 64 + (((ks * 4 + kg) ^ (row & 7)) * 8)]);
                }
#pragma unroll
                for (int nj = 0; nj < 2; ++nj) {
                    int qr = wave * 32 + nj * 16 + lr;
                    bq[nj] = __builtin_bit_cast(bf16x8,
                        *(const u16x8*)&Qs[qr * 64 + (((ks * 4 + kg) ^ (qr & 7)) * 8)]);
                }
#pragma unroll
                for (int mi = 0; mi < 4; ++mi)
#pragma unroll
                    for (int nj = 0; nj < 2; ++nj)
                        sacc[mi][nj] = __builtin_amdgcn_mfma_f32_16x16x32_bf16(
                            af[mi], bq[nj], sacc[mi][nj], 0, 0, 0);
            }

            if (kt >= 2 * qt) {         // diagonal tiles: causal mask
#pragma unroll
                for (int mi = 0; mi < 4; ++mi)
#pragma unroll
                    for (int nj = 0; nj < 2; ++nj)
#pragma unroll
                        for (int r = 0; r < 4; ++r) {
                            int kk_g = kt * 64 + mi * 16 + kg * 4 + r;
                            int q_g  = qt * 128 + wave * 32 + nj * 16 + lr;
                            if (kk_g > q_g) sacc[mi][nj][r] = -1e30f;
                        }
            }

            // p = exp2(s); accumulate row-sums per-lane; pack via v_perm
#pragma unroll
            for (int nj = 0; nj < 2; ++nj) {
                int q = wave * 32 + nj * 16 + lr;
                float lsum = 0.f;
#pragma unroll
                for (int mi = 0; mi < 4; ++mi) {
                    float p0 = __builtin_amdgcn_exp2f(sacc[mi][nj][0]);
                    float p1 = __builtin_amdgcn_exp2f(sacc[mi][nj][1]);
                    float p2 = __builtin_amdgcn_exp2f(sacc[mi][nj][2]);
                    float p3 = __builtin_amdgcn_exp2f(sacc[mi][nj][3]);
                    lsum += (p0 + p1) + (p2 + p3);
                    int kkc = mi * 2 + (kg >> 1);      // kk chunk = kk>>3
                    int off = q * 64 + ((kkc ^ (q & 7)) * 8) + (kg & 1) * 4;
                    uint2 w2;
                    w2.x = pack_bf2(p0, p1);
                    w2.y = pack_bf2(p2, p3);
                    *(uint2*)&Ps[off] = w2;
                }
                l_acc[nj] += lsum;
            }

            // PV: O += P * V^T
#pragma unroll
            for (int ks = 0; ks < 2; ++ks) {
                bf16x8 ap[2], bv[4];
#pragma unroll
                for (int mi = 0; mi < 2; ++mi) {
                    int q = wave * 32 + mi * 16 + lr;
                    ap[mi] = __builtin_bit_cast(bf16x8,
                        *(const u16x8*)&Ps[q * 64 + (((ks * 4 + kg) ^ (q & 7)) * 8)]);
                }
#pragma unroll
                for (int nj = 0; nj < 4; ++nj) {
                    int hd = nj * 16 + lr;
                    bv[nj] = __builtin_bit_cast(bf16x8,
                        *(const u16x8*)&Vs[hd * 64 + (((ks * 4 + kg) ^ (hd & 7)) * 8)]);
                }
#pragma unroll
                for (int mi = 0; mi < 2; ++mi)
#pragma unroll
                    for (int nj = 0; nj < 4; ++nj)
                        oacc[mi][nj] = __builtin_amdgcn_mfma_f32_16x16x32_bf16(
                            ap[mi], bv[nj], oacc[mi][nj], 0, 0, 0);
            }
        }
    }

    // epilogue: reduce l across kg-lanes, O /= l, write bf16 [B,S,H*HD]
#pragma unroll
    for (int nj = 0; nj < 2; ++nj) {
        float l = l_acc[nj];
        l += __shfl_xor(l, 16);
        l += __shfl_xor(l, 32);
        if (kg == 0) red[wave * 32 + nj * 16 + lr] = l;
    }
#pragma unroll
    for (int mi = 0; mi < 2; ++mi) {
        f32x4 lv = *(f32x4*)&red[wave * 32 + mi * 16 + kg * 4];
        f32x4 rv;
#pragma unroll
        for (int r = 0; r < 4; ++r) rv[r] = __builtin_amdgcn_rcpf(lv[r]);
#pragma unroll
        for (int nj = 0; nj < 4; ++nj)
#pragma unroll
            for (int r = 0; r < 4; ++r) {
                int q_local = wave * 32 + mi * 16 + kg * 4 + r;
                size_t row = (size_t)b * 1024 + qt * 128 + q_local;
                O[row * 1024 + h * 64 + nj * 16 + lr] =
                    f2bf(oacc[mi][nj][r] * rv[r]);
            }
    }
}

// ---------------------------------------------------------------------------
extern "C" void kernel_launch(void* const* d_in, const int* in_sizes, int n_in,
                              void* d_out, int out_size, void* d_ws, size_t ws_size,
                              hipStream_t stream) {
    const float* x   = (const float*)d_in[0];
    const float* Wq  = (const float*)d_in[1];
    const float* Wk  = (const float*)d_in[2];
    const float* Wv  = (const float*)d_in[3];
    const float* Wqd = (const float*)d_in[4];
    const float* Wkd = (const float*)d_in[5];
    const float* Wvd = (const float*)d_in[6];
    const float* Wo  = (const float*)d_in[7];
    float* out = (float*)d_out;

    char* ws = (char*)d_ws;
    u16*   WTcat  = (u16*)(ws);                    //  6 MB  [3072][1024] bf16
    u16*   WoT    = (u16*)(ws + 6291456);          //  2 MB
    u16*   xb     = (u16*)(ws + 8388608);          // 16 MB  [8192][1024] bf16
    u16*   q_attn = (u16*)(ws + 25165824);         // 16 MB  [B,S,D] bf16 (prescaled)
    u16*   k_attn = (u16*)(ws + 41943040);         // 16 MB  [B,S,D] bf16
    u16*   vT     = (u16*)(ws + 58720256);         // 16 MB  [B,H,64,S]
    u16*   Ow     = (u16*)(ws + 75497472);         // 16 MB  [8192][1024]
    float* part   = (float*)(ws + 92274688);       // 12 MB  partials

    cvt_fused<<<dim3(32, 32, 12), 256, 0, stream>>>(
        Wq, Wk, Wv, Wo, WTcat, WoT, (const float4*)x, xb);
    gemm_qkv<<<dim3(12, 64), 512, 0, stream>>>(xb, WTcat, out, q_attn, k_attn);
    ded_partial<<<dim3(8, 16, 3), 256, 0, stream>>>(x, Wqd, Wkd, Wvd, part);
    fix_vt<<<dim3(2432), 256, 0, stream>>>(
        part, out, q_attn, k_attn, out + (size_t)2 * BSD, vT);
    attn<<<dim3(8, 16, 8), 256, 0, stream>>>(q_attn, k_attn, vT, Ow);
    gemm8p_wo<<<dim3(4, 64), 512, 0, stream>>>(Ow, WoT, out);
}

// Round 5
// 456.545 us; speedup vs baseline: 1.0388x; 1.0054x over previous
//
#include <hip/hip_runtime.h>
#include <cstdint>

// ---------------------------------------------------------------------------
// MixedMHA: x[8,1024,1024] -> (output, k, v), causal MHA with per-token
// dedicated QKV weights for the first 16 tokens.
// Round 5: gemm_qkv gets a 3-buffer, 2-tiles-ahead counted-vmcnt pipeline
// (round-4 post-mortem: the per-tile WAITV(0) full drain ~200cyc after issue
// was the stall; m218: counted-vmcnt IS the 8-phase gain).
//   - LDS 3x(16+32)KB = 144 KB, tile t in buf t%3
//   - during tile t: stage tile t+2 into buf (t-1)%3 (reads done pre-barrier)
//   - end-of-t gate: vmcnt(6) (12 outstanding -> retire exactly tile t+1)
//   - drain-to-0 only at t=14 (tail); never in steady state
// Everything else byte-identical to round 4 (proven).
// ---------------------------------------------------------------------------

typedef unsigned short u16;
typedef __attribute__((ext_vector_type(8)))  __bf16 bf16x8;
typedef __attribute__((ext_vector_type(8)))  u16    u16x8;
typedef __attribute__((ext_vector_type(4)))  float  f32x4;

#define BSD   (8u * 1024u * 1024u)      // one [B,S,D] section in d_out
#define QSCALE 0.18033688011112042f     // 0.125 * log2(e): softmax in exp2 units

__device__ __forceinline__ u16 f2bf(float f) {
    unsigned u = __builtin_bit_cast(unsigned, f);
    u += 0x7fffu + ((u >> 16) & 1u);            // RNE
    return (u16)(u >> 16);
}

// pack hi16(p1):hi16(p0) in one v_perm_b32 (bf16 truncation)
__device__ __forceinline__ unsigned pack_bf2(float p0, float p1) {
    return __builtin_amdgcn_perm(__builtin_bit_cast(unsigned, p1),
                                 __builtin_bit_cast(unsigned, p0), 0x07060302u);
}

__device__ __forceinline__ void gl_lds16(const void* g, void* l) {
    __builtin_amdgcn_global_load_lds(
        (const __attribute__((address_space(1))) unsigned*)g,
        (__attribute__((address_space(3))) unsigned*)l, 16, 0, 0);
}

#define FENCE asm volatile("" ::: "memory")
#define WAITV(n) asm volatile("s_waitcnt vmcnt(" #n ")" ::: "memory")

// ---------------------------------------------------------------------------
// 1. Fused converts (independent block families, no shared state).
// ---------------------------------------------------------------------------
__global__ __launch_bounds__(256) void cvt_fused(
        const float* __restrict__ Wq, const float* __restrict__ Wk,
        const float* __restrict__ Wv, const float* __restrict__ Wo,
        u16* __restrict__ WTcat, u16* __restrict__ WoT,
        const float4* __restrict__ x, u16* __restrict__ xb) {
    __shared__ float t[32][33];
    int z = blockIdx.z;
    if (z < 4) {
        const float* src = (z == 0) ? Wq : (z == 1) ? Wk : (z == 2) ? Wv : Wo;
        u16* dst = (z < 3) ? (WTcat + (size_t)z * 1024 * 1024) : WoT;
        int k0 = blockIdx.x * 32, n0 = blockIdx.y * 32;
        int xx = threadIdx.x & 31, yy = threadIdx.x >> 5;   // 32 x 8
#pragma unroll
        for (int i = 0; i < 4; ++i)
            t[yy + 8 * i][xx] = src[(size_t)(k0 + yy + 8 * i) * 1024 + n0 + xx];
        __syncthreads();
#pragma unroll
        for (int i = 0; i < 4; ++i)
            dst[(size_t)(n0 + yy + 8 * i) * 1024 + k0 + xx] = f2bf(t[xx][yy + 8 * i]);
    } else {
        int lb = (z - 4) * 1024 + blockIdx.y * 32 + blockIdx.x;  // 8192 blocks
        int i = lb * 256 + threadIdx.x;                          // 2M float4
        float4 v = x[i];
        ushort4 o;
        o.x = f2bf(v.x); o.y = f2bf(v.y); o.z = f2bf(v.z); o.w = f2bf(v.w);
        ((ushort4*)xb)[i] = o;
    }
}

// ---------------------------------------------------------------------------
// 2. gemm_qkv: C = A[8192,1024] * Bt[3072,1024]^T with fused QKV epilogue.
// BM=128 BN=256 BK=64, 8 waves (2Mx4N), per-wave C = 64x64 (f32x4[4][4]).
// 3-buffer 2-ahead pipeline, tile t in buf t%3:
//   tile t, phase ks=0: 8 ds_read_b128 -> stage tile t+2 (6 gl_lds) -> 16 MFMA
//   tile t, phase ks=1: 8 ds_read_b128 -> 16 MFMA
//   end-of-t (t<15): vmcnt gate + barrier.
// vmcnt ledger (6 loads/thread/tile, in-order retirement):
//   prologue: stage(0),stage(1) -> 12 out; WAITV(6) retires tile0. barrier.
//   t<=13: out = stage(t+1)+stage(t+2) = 12; WAITV(6) retires tile t+1.
//   t=14:  out = stage(15) = 6; WAITV(0) (tail drain, once).
// WAR safety: stage(t+2) targets buf (t-1)%3, whose last reads completed
// before the end-of-(t-1) barrier; stage is issued after it. Uniform CFG.
// ---------------------------------------------------------------------------
__global__ __launch_bounds__(512, 2) void gemm_qkv(
        const u16* __restrict__ A, const u16* __restrict__ Bt,
        float* __restrict__ fout, u16* __restrict__ q_attn,
        u16* __restrict__ k_attn) {
    const int K = 1024, NT = 16;
    __shared__ u16 As[3][128 * 64];      // 48 KB
    __shared__ u16 Bs[3][256 * 64];      // 96 KB
    int tid = threadIdx.x;
    int w = tid >> 6, lane = tid & 63;
    int m0 = blockIdx.y * 128, n0 = blockIdx.x * 256;
    int wm = w & 1, wn = w >> 1;         // 2M x 4N waves
    int lr = lane & 15, kg = lane >> 4;

    f32x4 acc[4][4] = {};

    // stage full tile t into buf: A 2 sweeps + B 4 sweeps (6 gl_lds/thread)
    auto stageAll = [&](int buf, int t) {
#pragma unroll
        for (int s = 0; s < 2; ++s) {
            int ci = s * 512 + tid;
            int row = ci >> 3, cg = (ci & 7) ^ (row & 7);
            gl_lds16(A + (size_t)(m0 + row) * K + t * 64 + cg * 8, &As[buf][ci * 8]);
        }
#pragma unroll
        for (int s = 0; s < 4; ++s) {
            int ci = s * 512 + tid;
            int row = ci >> 3, cg = (ci & 7) ^ (row & 7);
            gl_lds16(Bt + (size_t)(n0 + row) * K + t * 64 + cg * 8, &Bs[buf][ci * 8]);
        }
    };

    stageAll(0, 0);
    stageAll(1, 1);
    WAITV(6);                            // tile 0 resident; tile 1 in flight
    FENCE; __builtin_amdgcn_s_barrier(); FENCE;

    int cur = 0;
    for (int t = 0; t < NT; ++t) {
        int stb = cur + 2; if (stb >= 3) stb -= 3;   // buf of tile t+2
        const u16* Ac = As[cur];
        const u16* Bc = Bs[cur];
        // ---- phase ks = 0
        {
            bf16x8 af[4], bf[4];
#pragma unroll
            for (int mi = 0; mi < 4; ++mi) {
                int row = wm * 64 + mi * 16 + lr;
                af[mi] = __builtin_bit_cast(bf16x8,
                    *(const u16x8*)&Ac[row * 64 + ((kg ^ (row & 7)) * 8)]);
            }
#pragma unroll
            for (int ni = 0; ni < 4; ++ni) {
                int row = wn * 64 + ni * 16 + lr;
                bf[ni] = __builtin_bit_cast(bf16x8,
                    *(const u16x8*)&Bc[row * 64 + ((kg ^ (row & 7)) * 8)]);
            }
            if (t + 2 < NT) stageAll(stb, t + 2);
            __builtin_amdgcn_s_setprio(1);
#pragma unroll
            for (int mi = 0; mi < 4; ++mi)
#pragma unroll
                for (int ni = 0; ni < 4; ++ni)
                    acc[mi][ni] = __builtin_amdgcn_mfma_f32_16x16x32_bf16(
                        af[mi], bf[ni], acc[mi][ni], 0, 0, 0);
            __builtin_amdgcn_s_setprio(0);
        }
        // ---- phase ks = 1
        {
            bf16x8 af[4], bf[4];
#pragma unroll
            for (int mi = 0; mi < 4; ++mi) {
                int row = wm * 64 + mi * 16 + lr;
                af[mi] = __builtin_bit_cast(bf16x8,
                    *(const u16x8*)&Ac[row * 64 + (((4 + kg) ^ (row & 7)) * 8)]);
            }
#pragma unroll
            for (int ni = 0; ni < 4; ++ni) {
                int row = wn * 64 + ni * 16 + lr;
                bf[ni] = __builtin_bit_cast(bf16x8,
                    *(const u16x8*)&Bc[row * 64 + (((4 + kg) ^ (row & 7)) * 8)]);
            }
            __builtin_amdgcn_s_setprio(1);
#pragma unroll
            for (int mi = 0; mi < 4; ++mi)
#pragma unroll
                for (int ni = 0; ni < 4; ++ni)
                    acc[mi][ni] = __builtin_amdgcn_mfma_f32_16x16x32_bf16(
                        af[mi], bf[ni], acc[mi][ni], 0, 0, 0);
            __builtin_amdgcn_s_setprio(0);
        }
        if (t < NT - 1) {
            if (t + 2 < NT) { WAITV(6); }    // steady state: tile t+1 resident
            else            { WAITV(0); }    // t=14 tail drain (tile 15)
            FENCE; __builtin_amdgcn_s_barrier(); FENCE;
        }
        cur = cur + 1; if (cur >= 3) cur -= 3;
    }

    int matId = n0 >> 10;                  // 0=q 1=k 2=v
    int ncol0 = (n0 & 1023) + wn * 64;
#pragma unroll
    for (int am = 0; am < 4; ++am) {
        int mbase = m0 + wm * 64 + am * 16 + kg * 4;
#pragma unroll
        for (int bn = 0; bn < 4; ++bn) {
            int col = ncol0 + bn * 16 + lr;
#pragma unroll
            for (int r = 0; r < 4; ++r) {
                int mm = mbase + r;
                float v = acc[am][bn][r];
                size_t idx = (size_t)mm * 1024 + col;
                if (matId == 0) {
                    q_attn[idx] = f2bf(v * QSCALE);   // 1/sqrt(64)*log2e
                } else if (matId == 1) {
                    fout[(size_t)BSD + idx] = v;
                    k_attn[idx] = f2bf(v);
                } else {
                    fout[(size_t)2 * BSD + idx] = v;
                }
            }
        }
    }
}

// ---------------------------------------------------------------------------
// 6. gemm8p_wo (round-3 exact; kept — measured-fast for the Wo GEMM).
// ---------------------------------------------------------------------------
#define LDfrag(BUF, bufi, row, ks)                                            \
    __builtin_bit_cast(bf16x8, *(const u16x8*)&BUF[bufi]                      \
        [(row) * 64 + ((((ks) * 4 + kg) ^ ((row) & 7)) * 8)])

#define PH(bufi, mh, nh, STAGE_STMT, GATE_STMT) do {                          \
    bf16x8 af_[2][2], bq_[2][2];                                              \
    _Pragma("unroll") for (int mi = 0; mi < 2; ++mi) {                        \
        int arow = wm * 64 + (mh) * 32 + mi * 16 + lr;                        \
        _Pragma("unroll") for (int ks = 0; ks < 2; ++ks)                      \
            af_[mi][ks] = LDfrag(As, bufi, arow, ks);                         \
    }                                                                         \
    _Pragma("unroll") for (int ni = 0; ni < 2; ++ni) {                        \
        int brow = wn * 64 + (nh) * 32 + ni * 16 + lr;                        \
        _Pragma("unroll") for (int ks = 0; ks < 2; ++ks)                      \
            bq_[ni][ks] = LDfrag(Bs, bufi, brow, ks);                         \
    }                                                                         \
    STAGE_STMT;                                                               \
    GATE_STMT;                                                                \
    FENCE; __builtin_amdgcn_s_barrier(); FENCE;                               \
    asm volatile("s_waitcnt lgkmcnt(0)" ::: "memory");                        \
    __builtin_amdgcn_s_setprio(1);                                            \
    _Pragma("unroll") for (int ks = 0; ks < 2; ++ks)                          \
    _Pragma("unroll") for (int mi = 0; mi < 2; ++mi)                          \
    _Pragma("unroll") for (int ni = 0; ni < 2; ++ni)                          \
        acc[(mh) * 2 + mi][(nh) * 2 + ni] =                                   \
            __builtin_amdgcn_mfma_f32_16x16x32_bf16(                          \
                af_[mi][ks], bq_[ni][ks],                                     \
                acc[(mh) * 2 + mi][(nh) * 2 + ni], 0, 0, 0);                  \
    __builtin_amdgcn_s_setprio(0);                                            \
    FENCE; __builtin_amdgcn_s_barrier(); FENCE;                               \
} while (0)

__global__ __launch_bounds__(512, 2) void gemm8p_wo(
        const u16* __restrict__ A, const u16* __restrict__ Bt,
        float* __restrict__ fout) {
    const int K = 1024, nt = 16;
    __shared__ u16 As[2][128 * 64];      // 32 KB
    __shared__ u16 Bs[2][256 * 64];      // 64 KB
    int tid = threadIdx.x;
    int w = tid >> 6, lane = tid & 63;
    int m0 = blockIdx.y * 128, n0 = blockIdx.x * 256;
    int wm = w & 1, wn = w >> 1;         // 2M x 4N waves
    int lr = lane & 15, kg = lane >> 4;

    f32x4 acc[4][4] = {};

    auto stageA = [&](int buf, int half, int t) {
        int ci = ((w & 3) << 6) + lane + ((w >> 2) << 9) + (half << 8);
        int row = ci >> 3, cg = (ci & 7) ^ (row & 7);
        gl_lds16(A + (size_t)(m0 + row) * K + t * 64 + cg * 8, &As[buf][ci * 8]);
    };
    auto stageB = [&](int buf, int half, int t) {
#pragma unroll
        for (int j = 0; j < 2; ++j) {
            int u = w + 8 * j;
            int ci = ((u >> 2) << 9) + ((u & 3) << 6) + lane + (half << 8);
            int row = ci >> 3, cg = (ci & 7) ^ (row & 7);
            gl_lds16(Bt + (size_t)(n0 + row) * K + t * 64 + cg * 8, &Bs[buf][ci * 8]);
        }
    };

    stageA(0, 0, 0);
    stageB(0, 0, 0);
    stageA(0, 1, 0);
    stageB(0, 1, 0);
    WAITV(3);
    FENCE; __builtin_amdgcn_s_barrier(); FENCE;

    for (int t = 0; t < nt - 1; ++t) {
        int cur = t & 1, nxt = cur ^ 1;
        PH(cur, 0, 0, stageA(nxt, 0, t + 1), WAITV(3));
        PH(cur, 1, 0, stageB(nxt, 0, t + 1), WAITV(3));
        PH(cur, 1, 1, stageA(nxt, 1, t + 1), ((void)0));
        PH(cur, 0, 1, stageB(nxt, 1, t + 1), WAITV(3));
    }
    PH(1, 0, 0, ((void)0), WAITV(2));
    PH(1, 1, 0, ((void)0), WAITV(0));
    PH(1, 1, 1, ((void)0), ((void)0));
    PH(1, 0, 1, ((void)0), ((void)0));

#pragma unroll
    for (int am = 0; am < 4; ++am) {
        int mbase = m0 + wm * 64 + am * 16 + kg * 4;
#pragma unroll
        for (int bn = 0; bn < 4; ++bn) {
            int col = n0 + wn * 64 + bn * 16 + lr;
#pragma unroll
            for (int r = 0; r < 4; ++r)
                fout[(size_t)(mbase + r) * 1024 + col] = acc[am][bn][r];
        }
    }
}

// ---------------------------------------------------------------------------
// 3. Dedicated projections, fp32 partials over d-chunks (round-0 exact).
// ---------------------------------------------------------------------------
__global__ __launch_bounds__(256) void ded_partial(
        const float* __restrict__ x, const float* __restrict__ Wq,
        const float* __restrict__ Wk, const float* __restrict__ Wv,
        float* __restrict__ part) {
    int dc = blockIdx.x, n = blockIdx.y, mat = blockIdx.z;
    const float* W = ((mat == 0) ? Wq : (mat == 1) ? Wk : Wv) +
                     (size_t)n * 1024 * 1024;
    __shared__ float xs[8 * 128];
    int t = threadIdx.x;
    for (int i = t; i < 1024; i += 256) {
        int b = i >> 7, d = i & 127;
        xs[i] = x[((size_t)b * 1024 + n) * 1024 + dc * 128 + d];
    }
    __syncthreads();
    int o0 = t * 4;
    float4 acc[8];
#pragma unroll
    for (int b = 0; b < 8; ++b) acc[b] = make_float4(0.f, 0.f, 0.f, 0.f);
    for (int d = 0; d < 128; d += 4) {
        float4 w0 = *(const float4*)&W[(size_t)(dc * 128 + d + 0) * 1024 + o0];
        float4 w1 = *(const float4*)&W[(size_t)(dc * 128 + d + 1) * 1024 + o0];
        float4 w2 = *(const float4*)&W[(size_t)(dc * 128 + d + 2) * 1024 + o0];
        float4 w3 = *(const float4*)&W[(size_t)(dc * 128 + d + 3) * 1024 + o0];
#pragma unroll
        for (int b = 0; b < 8; ++b) {
            float x0 = xs[b * 128 + d], x1 = xs[b * 128 + d + 1];
            float x2 = xs[b * 128 + d + 2], x3 = xs[b * 128 + d + 3];
            acc[b].x += x0 * w0.x + x1 * w1.x + x2 * w2.x + x3 * w3.x;
            acc[b].y += x0 * w0.y + x1 * w1.y + x2 * w2.y + x3 * w3.y;
            acc[b].z += x0 * w0.z + x1 * w1.z + x2 * w2.z + x3 * w3.z;
            acc[b].w += x0 * w0.w + x1 * w1.w + x2 * w2.w + x3 * w3.w;
        }
    }
#pragma unroll
    for (int b = 0; b < 8; ++b)
        *(float4*)&part[(size_t)(((mat * 8 + dc) * 8 + b) * 16 + n) * 1024 + o0] = acc[b];
}

// ---------------------------------------------------------------------------
// 4. Fused fixup + vT build (disjoint block families; round-2 exact).
// ---------------------------------------------------------------------------
__global__ __launch_bounds__(256) void fix_vt(
        const float* __restrict__ part, float* __restrict__ d_out,
        u16* __restrict__ q_attn, u16* __restrict__ k_attn,
        const float* __restrict__ vf, u16* __restrict__ vT) {
    __shared__ float t[64][65];
    int bid = blockIdx.x;
    int tid = threadIdx.x;

    if (bid < 384) {
        // ---- ded_fixup
        int mat = bid >> 7, b = (bid >> 4) & 7, n = bid & 15;
        int o0 = tid * 4;
        float v[4] = {0.f, 0.f, 0.f, 0.f};
        for (int dc = 0; dc < 8; ++dc) {
            float4 p = *(const float4*)&part[(size_t)(((mat * 8 + dc) * 8 + b) * 16 + n) * 1024 + o0];
            v[0] += p.x; v[1] += p.y; v[2] += p.z; v[3] += p.w;
        }
#pragma unroll
        for (int j = 0; j < 4; ++j) {
            int col = o0 + j;
            size_t idx = ((size_t)b * 1024 + n) * 1024 + col;
            if (mat == 0) {
                q_attn[idx] = f2bf(v[j] * QSCALE);
            } else if (mat == 1) {
                d_out[(size_t)BSD + idx] = v[j];
                k_attn[idx] = f2bf(v[j]);
            } else {
                d_out[(size_t)2 * BSD + idx] = v[j];
                // vT slot for this (token<16, col): transpose blocks skip it
                int h = col >> 6, hd = col & 63;
                vT[((size_t)((b * 16 + h) * 64 + hd)) * 1024 + n] = f2bf(v[j]);
            }
        }
        return;
    }

    // ---- v_transpose: read v fp32 [B,S,H,HD] (L3-hot), write vT bf16 [B,H,HD,S]
    int id = bid - 384;
    int st = id & 15, h = (id >> 4) & 15, b = id >> 8;
    int cg = tid & 15, sl = tid >> 4;      // 16 hd-groups x 16 s-rows
#pragma unroll
    for (int p = 0; p < 4; ++p) {
        int s = p * 16 + sl;
        float4 v = *(const float4*)&vf[
            ((size_t)(b * 1024 + st * 64 + s)) * 1024 + h * 64 + cg * 4];
        t[cg * 4 + 0][s] = v.x;
        t[cg * 4 + 1][s] = v.y;
        t[cg * 4 + 2][s] = v.z;
        t[cg * 4 + 3][s] = v.w;
    }
    __syncthreads();
    int hd = tid >> 2, sc = (tid & 3) * 16;
    if (st == 0 && sc == 0) return;        // s<16 handled by fixup blocks
    u16* dst = vT + ((size_t)((b * 16 + h) * 64 + hd)) * 1024 + st * 64 + sc;
#pragma unroll
    for (int c = 0; c < 4; ++c) {
        ushort4 o;
        o.x = f2bf(t[hd][sc + c * 4 + 0]);
        o.y = f2bf(t[hd][sc + c * 4 + 1]);
        o.z = f2bf(t[hd][sc + c * 4 + 2]);
        o.w = f2bf(t[hd][sc + c * 4 + 3]);
        *(ushort4*)(dst + c * 4) = o;
    }
}

// ---------------------------------------------------------------------------
// 5. Flash attention, fixed-reference softmax (round-0 exact).
// ---------------------------------------------------------------------------
__global__ __launch_bounds__(256) void attn(
        const u16* __restrict__ q_attn, const u16* __restrict__ k_attn,
        const u16* __restrict__ vT, u16* __restrict__ O) {
    int qt = 7 - blockIdx.x;               // long-pole blocks first
    int h = blockIdx.y, b = blockIdx.z;
    const u16* Qg = q_attn + ((size_t)(b * 1024) + qt * 128) * 1024 + h * 64;
    const u16* Kg = k_attn + ((size_t)(b * 1024)) * 1024 + h * 64;
    const u16* Vg = vT + (size_t)((b * 16 + h) * 64) * 1024;

    __shared__ u16 Qs[128 * 64];
    __shared__ u16 Ks[64 * 64];
    __shared__ u16 Vs[64 * 64];     // V^T tile: [hd][kk]
    __shared__ u16 Ps[128 * 64];    // P: [q][kk], per-wave private rows
    __shared__ float red[4 * 32];   // per-wave l broadcast (epilogue only)

    int tid = threadIdx.x, wave = tid >> 6, lane = tid & 63;
    int lr = lane & 15, kg = lane >> 4;

#pragma unroll
    for (int j = 0; j < 4; ++j) {   // Q: 1024 16B chunks, row stride 1024
        int ci = j * 256 + tid;
        int row = ci >> 3, cg = (ci & 7) ^ (row & 7);
        gl_lds16(Qg + (size_t)row * 1024 + cg * 8, Qs + ci * 8);
    }

    float l_acc[2] = {0.f, 0.f};
    f32x4 oacc[2][4] = {};

    int nkt = 2 * qt + 2;
    for (int kt = 0; kt < nkt; ++kt) {
        __syncthreads();            // prev-iter LDS reads done
#pragma unroll
        for (int j = 0; j < 2; ++j) {   // K,V tiles: 512 chunks each
            int ci = j * 256 + tid;
            int row = ci >> 3, cg = (ci & 7) ^ (row & 7);
            gl_lds16(Kg + (size_t)(kt * 64 + row) * 1024 + cg * 8, Ks + ci * 8);
            gl_lds16(Vg + (size_t)row * 1024 + kt * 64 + cg * 8, Vs + ci * 8);
        }
        __syncthreads();            // drains vmcnt (incl. Q on kt=0)

        // fully-masked wave on the top diagonal tile: contributes nothing
        bool wactive = (qt * 128 + wave * 32 + 31) >= kt * 64;
        if (wactive) {
            // S^T = K * Q^T : m=kk(64), n=q(32 per wave), k=hd
            f32x4 sacc[4][2] = {};
#pragma unroll
            for (int ks = 0; ks < 2; ++ks) {
                bf16x8 af[4], bq[2];
#pragma unroll
                for (int mi = 0; mi < 4; ++mi) {
                    int row = mi * 16 + lr;
                    af[mi] = __builtin_bit_cast(bf16x8,
                        *(const u16x8*)&Ks[row * 64 + (((ks * 4 + kg) ^ (row & 7)) * 8)]);
                }
#pragma unroll
                for (int nj = 0; nj < 2; ++nj) {
                    int qr = wave * 32 + nj * 16 + lr;
                    bq[nj] = __builtin_bit_cast(bf16x8,
                        *(const u16x8*)&Qs[qr * 64 + (((ks * 4 + kg) ^ (qr & 7)) * 8)]);
                }
#pragma unroll
                for (int mi = 0; mi < 4; ++mi)
#pragma unroll
                    for (int nj = 0; nj < 2; ++nj)
                        sacc[mi][nj] = __builtin_amdgcn_mfma_f32_16x16x32_bf16(
                            af[mi], bq[nj], sacc[mi][nj], 0, 0, 0);
            }

            if (kt >= 2 * qt) {         // diagonal tiles: causal mask
#pragma unroll
                for (int mi = 0; mi < 4; ++mi)
#pragma unroll
                    for (int nj = 0; nj < 2; ++nj)
#pragma unroll
                        for (int r = 0; r < 4; ++r) {
                            int kk_g = kt * 64 + mi * 16 + kg * 4 + r;
                            int q_g  = qt * 128 + wave * 32 + nj * 16 + lr;
                            if (kk_g > q_g) sacc[mi][nj][r] = -1e30f;
                        }
            }

            // p = exp2(s); accumulate row-sums per-lane; pack via v_perm
#pragma unroll
            for (int nj = 0; nj < 2; ++nj) {
                int q = wave * 32 + nj * 16 + lr;
                float lsum = 0.f;
#pragma unroll
                for (int mi = 0; mi < 4; ++mi) {
                    float p0 = __builtin_amdgcn_exp2f(sacc[mi][nj][0]);
                    float p1 = __builtin_amdgcn_exp2f(sacc[mi][nj][1]);
                    float p2 = __builtin_amdgcn_exp2f(sacc[mi][nj][2]);
                    float p3 = __builtin_amdgcn_exp2f(sacc[mi][nj][3]);
                    lsum += (p0 + p1) + (p2 + p3);
                    int kkc = mi * 2 + (kg >> 1);      // kk chunk = kk>>3
                    int off = q * 64 + ((kkc ^ (q & 7)) * 8) + (kg & 1) * 4;
                    uint2 w2;
                    w2.x = pack_bf2(p0, p1);
                    w2.y = pack_bf2(p2, p3);
                    *(uint2*)&Ps[off] = w2;
                }
                l_acc[nj] += lsum;
            }

            // PV: O += P * V^T
#pragma unroll
            for (int ks = 0; ks < 2; ++ks) {
                bf16x8 ap[2], bv[4];
#pragma unroll
                for (int mi = 0; mi < 2; ++mi) {
                    int q = wave * 32 + mi * 16 + lr;
                    ap[mi] = __builtin_bit_cast(bf16x8,
                        *(const u16x8*)&Ps[q * 64 + (((ks * 4 + kg) ^ (q & 7)) * 8)]);
                }
#pragma unroll
                for (int nj = 0; nj < 4; ++nj) {
                    int hd = nj * 16 + lr;
                    bv[nj] = __builtin_bit_cast(bf16x8,
                        *(const u16x8*)&Vs[hd * 64 + (((ks * 4 + kg) ^ (hd & 7)) * 8)]);
                }
#pragma unroll
                for (int mi = 0; mi < 2; ++mi)
#pragma unroll
                    for (int nj = 0; nj < 4; ++nj)
                        oacc[mi][nj] = __builtin_amdgcn_mfma_f32_16x16x32_bf16(
                            ap[mi], bv[nj], oacc[mi][nj], 0, 0, 0);
            }
        }
    }

    // epilogue: reduce l across kg-lanes, O /= l, write bf16 [B,S,H*HD]
#pragma unroll
    for (int nj = 0; nj < 2; ++nj) {
        float l = l_acc[nj];
        l += __shfl_xor(l, 16);
        l += __shfl_xor(l, 32);
        if (kg == 0) red[wave * 32 + nj * 16 + lr] = l;
    }
#pragma unroll
    for (int mi = 0; mi < 2; ++mi) {
        f32x4 lv = *(f32x4*)&red[wave * 32 + mi * 16 + kg * 4];
        f32x4 rv;
#pragma unroll
        for (int r = 0; r < 4; ++r) rv[r] = __builtin_amdgcn_rcpf(lv[r]);
#pragma unroll
        for (int nj = 0; nj < 4; ++nj)
#pragma unroll
            for (int r = 0; r < 4; ++r) {
                int q_local = wave * 32 + mi * 16 + kg * 4 + r;
                size_t row = (size_t)b * 1024 + qt * 128 + q_local;
                O[row * 1024 + h * 64 + nj * 16 + lr] =
                    f2bf(oacc[mi][nj][r] * rv[r]);
            }
    }
}

// ---------------------------------------------------------------------------
extern "C" void kernel_launch(void* const* d_in, const int* in_sizes, int n_in,
                              void* d_out, int out_size, void* d_ws, size_t ws_size,
                              hipStream_t stream) {
    const float* x   = (const float*)d_in[0];
    const float* Wq  = (const float*)d_in[1];
    const float* Wk  = (const float*)d_in[2];
    const float* Wv  = (const float*)d_in[3];
    const float* Wqd = (const float*)d_in[4];
    const float* Wkd = (const float*)d_in[5];
    const float* Wvd = (const float*)d_in[6];
    const float* Wo  = (const float*)d_in[7];
    float* out = (float*)d_out;

    char* ws = (char*)d_ws;
    u16*   WTcat  = (u16*)(ws);                    //  6 MB  [3072][1024] bf16
    u16*   WoT    = (u16*)(ws + 6291456);          //  2 MB
    u16*   xb     = (u16*)(ws + 8388608);          // 16 MB  [8192][1024] bf16
    u16*   q_attn = (u16*)(ws + 25165824);         // 16 MB  [B,S,D] bf16 (prescaled)
    u16*   k_attn = (u16*)(ws + 41943040);         // 16 MB  [B,S,D] bf16
    u16*   vT     = (u16*)(ws + 58720256);         // 16 MB  [B,H,64,S]
    u16*   Ow     = (u16*)(ws + 75497472);         // 16 MB  [8192][1024]
    float* part   = (float*)(ws + 92274688);       // 12 MB  partials

    cvt_fused<<<dim3(32, 32, 12), 256, 0, stream>>>(
        Wq, Wk, Wv, Wo, WTcat, WoT, (const float4*)x, xb);
    gemm_qkv<<<dim3(12, 64), 512, 0, stream>>>(xb, WTcat, out, q_attn, k_attn);
    ded_partial<<<dim3(8, 16, 3), 256, 0, stream>>>(x, Wqd, Wkd, Wvd, part);
    fix_vt<<<dim3(2432), 256, 0, stream>>>(
        part, out, q_attn, k_attn, out + (size_t)2 * BSD, vT);
    attn<<<dim3(8, 16, 8), 256, 0, stream>>>(q_attn, k_attn, vT, Ow);
    gemm8p_wo<<<dim3(4, 64), 512, 0, stream>>>(Ow, WoT, out);
}

// Round 6
// 455.757 us; speedup vs baseline: 1.0406x; 1.0017x over previous
//
#include <hip/hip_runtime.h>
#include <cstdint>

// ---------------------------------------------------------------------------
// MixedMHA: x[8,1024,1024] -> (output, k, v), causal MHA with per-token
// dedicated QKV weights for the first 16 tokens.
// Round 6: ded_partial restructured (round-5 counters: 82.7us, 1.37 TB/s,
// MfmaUtil 0, 6 waves/CU, 4-deep load pipeline -> latency-bound, matches
// 32iter x 900cyc / 1.5-wave-hiding). New version: 512 thr/block (12
// waves/CU), float2 per thread, 8 independent loads in flight per d-group
// (49 KB/CU in flight >> 9 KB needed for HBM saturation). Same grid, same
// part layout, same accumulation order -> fix_vt and numerics untouched.
// Everything else byte-identical to round 5.
// ---------------------------------------------------------------------------

typedef unsigned short u16;
typedef __attribute__((ext_vector_type(8)))  __bf16 bf16x8;
typedef __attribute__((ext_vector_type(8)))  u16    u16x8;
typedef __attribute__((ext_vector_type(4)))  float  f32x4;

#define BSD   (8u * 1024u * 1024u)      // one [B,S,D] section in d_out
#define QSCALE 0.18033688011112042f     // 0.125 * log2(e): softmax in exp2 units

__device__ __forceinline__ u16 f2bf(float f) {
    unsigned u = __builtin_bit_cast(unsigned, f);
    u += 0x7fffu + ((u >> 16) & 1u);            // RNE
    return (u16)(u >> 16);
}

// pack hi16(p1):hi16(p0) in one v_perm_b32 (bf16 truncation)
__device__ __forceinline__ unsigned pack_bf2(float p0, float p1) {
    return __builtin_amdgcn_perm(__builtin_bit_cast(unsigned, p1),
                                 __builtin_bit_cast(unsigned, p0), 0x07060302u);
}

__device__ __forceinline__ void gl_lds16(const void* g, void* l) {
    __builtin_amdgcn_global_load_lds(
        (const __attribute__((address_space(1))) unsigned*)g,
        (__attribute__((address_space(3))) unsigned*)l, 16, 0, 0);
}

#define FENCE asm volatile("" ::: "memory")
#define WAITV(n) asm volatile("s_waitcnt vmcnt(" #n ")" ::: "memory")

// ---------------------------------------------------------------------------
// 1. Fused converts (independent block families, no shared state).
// ---------------------------------------------------------------------------
__global__ __launch_bounds__(256) void cvt_fused(
        const float* __restrict__ Wq, const float* __restrict__ Wk,
        const float* __restrict__ Wv, const float* __restrict__ Wo,
        u16* __restrict__ WTcat, u16* __restrict__ WoT,
        const float4* __restrict__ x, u16* __restrict__ xb) {
    __shared__ float t[32][33];
    int z = blockIdx.z;
    if (z < 4) {
        const float* src = (z == 0) ? Wq : (z == 1) ? Wk : (z == 2) ? Wv : Wo;
        u16* dst = (z < 3) ? (WTcat + (size_t)z * 1024 * 1024) : WoT;
        int k0 = blockIdx.x * 32, n0 = blockIdx.y * 32;
        int xx = threadIdx.x & 31, yy = threadIdx.x >> 5;   // 32 x 8
#pragma unroll
        for (int i = 0; i < 4; ++i)
            t[yy + 8 * i][xx] = src[(size_t)(k0 + yy + 8 * i) * 1024 + n0 + xx];
        __syncthreads();
#pragma unroll
        for (int i = 0; i < 4; ++i)
            dst[(size_t)(n0 + yy + 8 * i) * 1024 + k0 + xx] = f2bf(t[xx][yy + 8 * i]);
    } else {
        int lb = (z - 4) * 1024 + blockIdx.y * 32 + blockIdx.x;  // 8192 blocks
        int i = lb * 256 + threadIdx.x;                          // 2M float4
        float4 v = x[i];
        ushort4 o;
        o.x = f2bf(v.x); o.y = f2bf(v.y); o.z = f2bf(v.z); o.w = f2bf(v.w);
        ((ushort4*)xb)[i] = o;
    }
}

// ---------------------------------------------------------------------------
// 2. gemm_qkv: C = A[8192,1024] * Bt[3072,1024]^T with fused QKV epilogue.
// BM=128 BN=256 BK=64, 8 waves (2Mx4N), per-wave C = 64x64 (f32x4[4][4]).
// 3-buffer 2-ahead pipeline, tile t in buf t%3 (round-5 exact).
// ---------------------------------------------------------------------------
__global__ __launch_bounds__(512, 2) void gemm_qkv(
        const u16* __restrict__ A, const u16* __restrict__ Bt,
        float* __restrict__ fout, u16* __restrict__ q_attn,
        u16* __restrict__ k_attn) {
    const int K = 1024, NT = 16;
    __shared__ u16 As[3][128 * 64];      // 48 KB
    __shared__ u16 Bs[3][256 * 64];      // 96 KB
    int tid = threadIdx.x;
    int w = tid >> 6, lane = tid & 63;
    int m0 = blockIdx.y * 128, n0 = blockIdx.x * 256;
    int wm = w & 1, wn = w >> 1;         // 2M x 4N waves
    int lr = lane & 15, kg = lane >> 4;

    f32x4 acc[4][4] = {};

    // stage full tile t into buf: A 2 sweeps + B 4 sweeps (6 gl_lds/thread)
    auto stageAll = [&](int buf, int t) {
#pragma unroll
        for (int s = 0; s < 2; ++s) {
            int ci = s * 512 + tid;
            int row = ci >> 3, cg = (ci & 7) ^ (row & 7);
            gl_lds16(A + (size_t)(m0 + row) * K + t * 64 + cg * 8, &As[buf][ci * 8]);
        }
#pragma unroll
        for (int s = 0; s < 4; ++s) {
            int ci = s * 512 + tid;
            int row = ci >> 3, cg = (ci & 7) ^ (row & 7);
            gl_lds16(Bt + (size_t)(n0 + row) * K + t * 64 + cg * 8, &Bs[buf][ci * 8]);
        }
    };

    stageAll(0, 0);
    stageAll(1, 1);
    WAITV(6);                            // tile 0 resident; tile 1 in flight
    FENCE; __builtin_amdgcn_s_barrier(); FENCE;

    int cur = 0;
    for (int t = 0; t < NT; ++t) {
        int stb = cur + 2; if (stb >= 3) stb -= 3;   // buf of tile t+2
        const u16* Ac = As[cur];
        const u16* Bc = Bs[cur];
        // ---- phase ks = 0
        {
            bf16x8 af[4], bf[4];
#pragma unroll
            for (int mi = 0; mi < 4; ++mi) {
                int row = wm * 64 + mi * 16 + lr;
                af[mi] = __builtin_bit_cast(bf16x8,
                    *(const u16x8*)&Ac[row * 64 + ((kg ^ (row & 7)) * 8)]);
            }
#pragma unroll
            for (int ni = 0; ni < 4; ++ni) {
                int row = wn * 64 + ni * 16 + lr;
                bf[ni] = __builtin_bit_cast(bf16x8,
                    *(const u16x8*)&Bc[row * 64 + ((kg ^ (row & 7)) * 8)]);
            }
            if (t + 2 < NT) stageAll(stb, t + 2);
            __builtin_amdgcn_s_setprio(1);
#pragma unroll
            for (int mi = 0; mi < 4; ++mi)
#pragma unroll
                for (int ni = 0; ni < 4; ++ni)
                    acc[mi][ni] = __builtin_amdgcn_mfma_f32_16x16x32_bf16(
                        af[mi], bf[ni], acc[mi][ni], 0, 0, 0);
            __builtin_amdgcn_s_setprio(0);
        }
        // ---- phase ks = 1
        {
            bf16x8 af[4], bf[4];
#pragma unroll
            for (int mi = 0; mi < 4; ++mi) {
                int row = wm * 64 + mi * 16 + lr;
                af[mi] = __builtin_bit_cast(bf16x8,
                    *(const u16x8*)&Ac[row * 64 + (((4 + kg) ^ (row & 7)) * 8)]);
            }
#pragma unroll
            for (int ni = 0; ni < 4; ++ni) {
                int row = wn * 64 + ni * 16 + lr;
                bf[ni] = __builtin_bit_cast(bf16x8,
                    *(const u16x8*)&Bc[row * 64 + (((4 + kg) ^ (row & 7)) * 8)]);
            }
            __builtin_amdgcn_s_setprio(1);
#pragma unroll
            for (int mi = 0; mi < 4; ++mi)
#pragma unroll
                for (int ni = 0; ni < 4; ++ni)
                    acc[mi][ni] = __builtin_amdgcn_mfma_f32_16x16x32_bf16(
                        af[mi], bf[ni], acc[mi][ni], 0, 0, 0);
            __builtin_amdgcn_s_setprio(0);
        }
        if (t < NT - 1) {
            if (t + 2 < NT) { WAITV(6); }    // steady state: tile t+1 resident
            else            { WAITV(0); }    // t=14 tail drain (tile 15)
            FENCE; __builtin_amdgcn_s_barrier(); FENCE;
        }
        cur = cur + 1; if (cur >= 3) cur -= 3;
    }

    int matId = n0 >> 10;                  // 0=q 1=k 2=v
    int ncol0 = (n0 & 1023) + wn * 64;
#pragma unroll
    for (int am = 0; am < 4; ++am) {
        int mbase = m0 + wm * 64 + am * 16 + kg * 4;
#pragma unroll
        for (int bn = 0; bn < 4; ++bn) {
            int col = ncol0 + bn * 16 + lr;
#pragma unroll
            for (int r = 0; r < 4; ++r) {
                int mm = mbase + r;
                float v = acc[am][bn][r];
                size_t idx = (size_t)mm * 1024 + col;
                if (matId == 0) {
                    q_attn[idx] = f2bf(v * QSCALE);   // 1/sqrt(64)*log2e
                } else if (matId == 1) {
                    fout[(size_t)BSD + idx] = v;
                    k_attn[idx] = f2bf(v);
                } else {
                    fout[(size_t)2 * BSD + idx] = v;
                }
            }
        }
    }
}

// ---------------------------------------------------------------------------
// 6. gemm8p_wo (round-3 exact; kept — measured-fast for the Wo GEMM).
// ---------------------------------------------------------------------------
#define LDfrag(BUF, bufi, row, ks)                                            \
    __builtin_bit_cast(bf16x8, *(const u16x8*)&BUF[bufi]                      \
        [(row) * 64 + ((((ks) * 4 + kg) ^ ((row) & 7)) * 8)])

#define PH(bufi, mh, nh, STAGE_STMT, GATE_STMT) do {                          \
    bf16x8 af_[2][2], bq_[2][2];                                              \
    _Pragma("unroll") for (int mi = 0; mi < 2; ++mi) {                        \
        int arow = wm * 64 + (mh) * 32 + mi * 16 + lr;                        \
        _Pragma("unroll") for (int ks = 0; ks < 2; ++ks)                      \
            af_[mi][ks] = LDfrag(As, bufi, arow, ks);                         \
    }                                                                         \
    _Pragma("unroll") for (int ni = 0; ni < 2; ++ni) {                        \
        int brow = wn * 64 + (nh) * 32 + ni * 16 + lr;                        \
        _Pragma("unroll") for (int ks = 0; ks < 2; ++ks)                      \
            bq_[ni][ks] = LDfrag(Bs, bufi, brow, ks);                         \
    }                                                                         \
    STAGE_STMT;                                                               \
    GATE_STMT;                                                                \
    FENCE; __builtin_amdgcn_s_barrier(); FENCE;                               \
    asm volatile("s_waitcnt lgkmcnt(0)" ::: "memory");                        \
    __builtin_amdgcn_s_setprio(1);                                            \
    _Pragma("unroll") for (int ks = 0; ks < 2; ++ks)                          \
    _Pragma("unroll") for (int mi = 0; mi < 2; ++mi)                          \
    _Pragma("unroll") for (int ni = 0; ni < 2; ++ni)                          \
        acc[(mh) * 2 + mi][(nh) * 2 + ni] =                                   \
            __builtin_amdgcn_mfma_f32_16x16x32_bf16(                          \
                af_[mi][ks], bq_[ni][ks],                                     \
                acc[(mh) * 2 + mi][(nh) * 2 + ni], 0, 0, 0);                  \
    __builtin_amdgcn_s_setprio(0);                                            \
    FENCE; __builtin_amdgcn_s_barrier(); FENCE;                               \
} while (0)

__global__ __launch_bounds__(512, 2) void gemm8p_wo(
        const u16* __restrict__ A, const u16* __restrict__ Bt,
        float* __restrict__ fout) {
    const int K = 1024, nt = 16;
    __shared__ u16 As[2][128 * 64];      // 32 KB
    __shared__ u16 Bs[2][256 * 64];      // 64 KB
    int tid = threadIdx.x;
    int w = tid >> 6, lane = tid & 63;
    int m0 = blockIdx.y * 128, n0 = blockIdx.x * 256;
    int wm = w & 1, wn = w >> 1;         // 2M x 4N waves
    int lr = lane & 15, kg = lane >> 4;

    f32x4 acc[4][4] = {};

    auto stageA = [&](int buf, int half, int t) {
        int ci = ((w & 3) << 6) + lane + ((w >> 2) << 9) + (half << 8);
        int row = ci >> 3, cg = (ci & 7) ^ (row & 7);
        gl_lds16(A + (size_t)(m0 + row) * K + t * 64 + cg * 8, &As[buf][ci * 8]);
    };
    auto stageB = [&](int buf, int half, int t) {
#pragma unroll
        for (int j = 0; j < 2; ++j) {
            int u = w + 8 * j;
            int ci = ((u >> 2) << 9) + ((u & 3) << 6) + lane + (half << 8);
            int row = ci >> 3, cg = (ci & 7) ^ (row & 7);
            gl_lds16(Bt + (size_t)(n0 + row) * K + t * 64 + cg * 8, &Bs[buf][ci * 8]);
        }
    };

    stageA(0, 0, 0);
    stageB(0, 0, 0);
    stageA(0, 1, 0);
    stageB(0, 1, 0);
    WAITV(3);
    FENCE; __builtin_amdgcn_s_barrier(); FENCE;

    for (int t = 0; t < nt - 1; ++t) {
        int cur = t & 1, nxt = cur ^ 1;
        PH(cur, 0, 0, stageA(nxt, 0, t + 1), WAITV(3));
        PH(cur, 1, 0, stageB(nxt, 0, t + 1), WAITV(3));
        PH(cur, 1, 1, stageA(nxt, 1, t + 1), ((void)0));
        PH(cur, 0, 1, stageB(nxt, 1, t + 1), WAITV(3));
    }
    PH(1, 0, 0, ((void)0), WAITV(2));
    PH(1, 1, 0, ((void)0), WAITV(0));
    PH(1, 1, 1, ((void)0), ((void)0));
    PH(1, 0, 1, ((void)0), ((void)0));

#pragma unroll
    for (int am = 0; am < 4; ++am) {
        int mbase = m0 + wm * 64 + am * 16 + kg * 4;
#pragma unroll
        for (int bn = 0; bn < 4; ++bn) {
            int col = n0 + wn * 64 + bn * 16 + lr;
#pragma unroll
            for (int r = 0; r < 4; ++r)
                fout[(size_t)(mbase + r) * 1024 + col] = acc[am][bn][r];
        }
    }
}

// ---------------------------------------------------------------------------
// 3. Dedicated projections (RESTRUCTURED): 512 thr/block, float2/thread,
// 8 independent loads in flight per d-group. Same grid (8,16,3), same part
// layout, same sequential-d accumulation order as before.
// ---------------------------------------------------------------------------
__global__ __launch_bounds__(512) void ded_partial(
        const float* __restrict__ x, const float* __restrict__ Wq,
        const float* __restrict__ Wk, const float* __restrict__ Wv,
        float* __restrict__ part) {
    int dc = blockIdx.x, n = blockIdx.y, mat = blockIdx.z;
    const float* W = ((mat == 0) ? Wq : (mat == 1) ? Wk : Wv) +
                     (size_t)n * 1024 * 1024;
    __shared__ float xs[8 * 128];
    int t = threadIdx.x;
    for (int i = t; i < 1024; i += 512) {
        int b = i >> 7, d = i & 127;
        xs[i] = x[((size_t)b * 1024 + n) * 1024 + dc * 128 + d];
    }
    __syncthreads();
    int o0 = t * 2;
    float2 acc[8];
#pragma unroll
    for (int b = 0; b < 8; ++b) acc[b] = make_float2(0.f, 0.f);
    for (int d0 = 0; d0 < 128; d0 += 8) {
        float2 w[8];
#pragma unroll
        for (int j = 0; j < 8; ++j)      // 8 independent loads in flight
            w[j] = *(const float2*)&W[(size_t)(dc * 128 + d0 + j) * 1024 + o0];
#pragma unroll
        for (int j = 0; j < 8; ++j) {
#pragma unroll
            for (int b = 0; b < 8; ++b) {
                float xv = xs[b * 128 + d0 + j];
                acc[b].x += xv * w[j].x;
                acc[b].y += xv * w[j].y;
            }
        }
    }
#pragma unroll
    for (int b = 0; b < 8; ++b)
        *(float2*)&part[(size_t)(((mat * 8 + dc) * 8 + b) * 16 + n) * 1024 + o0] = acc[b];
}

// ---------------------------------------------------------------------------
// 4. Fused fixup + vT build (disjoint block families; round-2 exact).
// ---------------------------------------------------------------------------
__global__ __launch_bounds__(256) void fix_vt(
        const float* __restrict__ part, float* __restrict__ d_out,
        u16* __restrict__ q_attn, u16* __restrict__ k_attn,
        const float* __restrict__ vf, u16* __restrict__ vT) {
    __shared__ float t[64][65];
    int bid = blockIdx.x;
    int tid = threadIdx.x;

    if (bid < 384) {
        // ---- ded_fixup
        int mat = bid >> 7, b = (bid >> 4) & 7, n = bid & 15;
        int o0 = tid * 4;
        float v[4] = {0.f, 0.f, 0.f, 0.f};
        for (int dc = 0; dc < 8; ++dc) {
            float4 p = *(const float4*)&part[(size_t)(((mat * 8 + dc) * 8 + b) * 16 + n) * 1024 + o0];
            v[0] += p.x; v[1] += p.y; v[2] += p.z; v[3] += p.w;
        }
#pragma unroll
        for (int j = 0; j < 4; ++j) {
            int col = o0 + j;
            size_t idx = ((size_t)b * 1024 + n) * 1024 + col;
            if (mat == 0) {
                q_attn[idx] = f2bf(v[j] * QSCALE);
            } else if (mat == 1) {
                d_out[(size_t)BSD + idx] = v[j];
                k_attn[idx] = f2bf(v[j]);
            } else {
                d_out[(size_t)2 * BSD + idx] = v[j];
                // vT slot for this (token<16, col): transpose blocks skip it
                int h = col >> 6, hd = col & 63;
                vT[((size_t)((b * 16 + h) * 64 + hd)) * 1024 + n] = f2bf(v[j]);
            }
        }
        return;
    }

    // ---- v_transpose: read v fp32 [B,S,H,HD] (L3-hot), write vT bf16 [B,H,HD,S]
    int id = bid - 384;
    int st = id & 15, h = (id >> 4) & 15, b = id >> 8;
    int cg = tid & 15, sl = tid >> 4;      // 16 hd-groups x 16 s-rows
#pragma unroll
    for (int p = 0; p < 4; ++p) {
        int s = p * 16 + sl;
        float4 v = *(const float4*)&vf[
            ((size_t)(b * 1024 + st * 64 + s)) * 1024 + h * 64 + cg * 4];
        t[cg * 4 + 0][s] = v.x;
        t[cg * 4 + 1][s] = v.y;
        t[cg * 4 + 2][s] = v.z;
        t[cg * 4 + 3][s] = v.w;
    }
    __syncthreads();
    int hd = tid >> 2, sc = (tid & 3) * 16;
    if (st == 0 && sc == 0) return;        // s<16 handled by fixup blocks
    u16* dst = vT + ((size_t)((b * 16 + h) * 64 + hd)) * 1024 + st * 64 + sc;
#pragma unroll
    for (int c = 0; c < 4; ++c) {
        ushort4 o;
        o.x = f2bf(t[hd][sc + c * 4 + 0]);
        o.y = f2bf(t[hd][sc + c * 4 + 1]);
        o.z = f2bf(t[hd][sc + c * 4 + 2]);
        o.w = f2bf(t[hd][sc + c * 4 + 3]);
        *(ushort4*)(dst + c * 4) = o;
    }
}

// ---------------------------------------------------------------------------
// 5. Flash attention, fixed-reference softmax (round-0 exact).
// ---------------------------------------------------------------------------
__global__ __launch_bounds__(256) void attn(
        const u16* __restrict__ q_attn, const u16* __restrict__ k_attn,
        const u16* __restrict__ vT, u16* __restrict__ O) {
    int qt = 7 - blockIdx.x;               // long-pole blocks first
    int h = blockIdx.y, b = blockIdx.z;
    const u16* Qg = q_attn + ((size_t)(b * 1024) + qt * 128) * 1024 + h * 64;
    const u16* Kg = k_attn + ((size_t)(b * 1024)) * 1024 + h * 64;
    const u16* Vg = vT + (size_t)((b * 16 + h) * 64) * 1024;

    __shared__ u16 Qs[128 * 64];
    __shared__ u16 Ks[64 * 64];
    __shared__ u16 Vs[64 * 64];     // V^T tile: [hd][kk]
    __shared__ u16 Ps[128 * 64];    // P: [q][kk], per-wave private rows
    __shared__ float red[4 * 32];   // per-wave l broadcast (epilogue only)

    int tid = threadIdx.x, wave = tid >> 6, lane = tid & 63;
    int lr = lane & 15, kg = lane >> 4;

#pragma unroll
    for (int j = 0; j < 4; ++j) {   // Q: 1024 16B chunks, row stride 1024
        int ci = j * 256 + tid;
        int row = ci >> 3, cg = (ci & 7) ^ (row & 7);
        gl_lds16(Qg + (size_t)row * 1024 + cg * 8, Qs + ci * 8);
    }

    float l_acc[2] = {0.f, 0.f};
    f32x4 oacc[2][4] = {};

    int nkt = 2 * qt + 2;
    for (int kt = 0; kt < nkt; ++kt) {
        __syncthreads();            // prev-iter LDS reads done
#pragma unroll
        for (int j = 0; j < 2; ++j) {   // K,V tiles: 512 chunks each
            int ci = j * 256 + tid;
            int row = ci >> 3, cg = (ci & 7) ^ (row & 7);
            gl_lds16(Kg + (size_t)(kt * 64 + row) * 1024 + cg * 8, Ks + ci * 8);
            gl_lds16(Vg + (size_t)row * 1024 + kt * 64 + cg * 8, Vs + ci * 8);
        }
        __syncthreads();            // drains vmcnt (incl. Q on kt=0)

        // fully-masked wave on the top diagonal tile: contributes nothing
        bool wactive = (qt * 128 + wave * 32 + 31) >= kt * 64;
        if (wactive) {
            // S^T = K * Q^T : m=kk(64), n=q(32 per wave), k=hd
            f32x4 sacc[4][2] = {};
#pragma unroll
            for (int ks = 0; ks < 2; ++ks) {
                bf16x8 af[4], bq[2];
#pragma unroll
                for (int mi = 0; mi < 4; ++mi) {
                    int row = mi * 16 + lr;
                    af[mi] = __builtin_bit_cast(bf16x8,
                        *(const u16x8*)&Ks[row * 64 + (((ks * 4 + kg) ^ (row & 7)) * 8)]);
                }
#pragma unroll
                for (int nj = 0; nj < 2; ++nj) {
                    int qr = wave * 32 + nj * 16 + lr;
                    bq[nj] = __builtin_bit_cast(bf16x8,
                        *(const u16x8*)&Qs[qr * 64 + (((ks * 4 + kg) ^ (qr & 7)) * 8)]);
                }
#pragma unroll
                for (int mi = 0; mi < 4; ++mi)
#pragma unroll
                    for (int nj = 0; nj < 2; ++nj)
                        sacc[mi][nj] = __builtin_amdgcn_mfma_f32_16x16x32_bf16(
                            af[mi], bq[nj], sacc[mi][nj], 0, 0, 0);
            }

            if (kt >= 2 * qt) {         // diagonal tiles: causal mask
#pragma unroll
                for (int mi = 0; mi < 4; ++mi)
#pragma unroll
                    for (int nj = 0; nj < 2; ++nj)
#pragma unroll
                        for (int r = 0; r < 4; ++r) {
                            int kk_g = kt * 64 + mi * 16 + kg * 4 + r;
                            int q_g  = qt * 128 + wave * 32 + nj * 16 + lr;
                            if (kk_g > q_g) sacc[mi][nj][r] = -1e30f;
                        }
            }

            // p = exp2(s); accumulate row-sums per-lane; pack via v_perm
#pragma unroll
            for (int nj = 0; nj < 2; ++nj) {
                int q = wave * 32 + nj * 16 + lr;
                float lsum = 0.f;
#pragma unroll
                for (int mi = 0; mi < 4; ++mi) {
                    float p0 = __builtin_amdgcn_exp2f(sacc[mi][nj][0]);
                    float p1 = __builtin_amdgcn_exp2f(sacc[mi][nj][1]);
                    float p2 = __builtin_amdgcn_exp2f(sacc[mi][nj][2]);
                    float p3 = __builtin_amdgcn_exp2f(sacc[mi][nj][3]);
                    lsum += (p0 + p1) + (p2 + p3);
                    int kkc = mi * 2 + (kg >> 1);      // kk chunk = kk>>3
                    int off = q * 64 + ((kkc ^ (q & 7)) * 8) + (kg & 1) * 4;
                    uint2 w2;
                    w2.x = pack_bf2(p0, p1);
                    w2.y = pack_bf2(p2, p3);
                    *(uint2*)&Ps[off] = w2;
                }
                l_acc[nj] += lsum;
            }

            // PV: O += P * V^T
#pragma unroll
            for (int ks = 0; ks < 2; ++ks) {
                bf16x8 ap[2], bv[4];
#pragma unroll
                for (int mi = 0; mi < 2; ++mi) {
                    int q = wave * 32 + mi * 16 + lr;
                    ap[mi] = __builtin_bit_cast(bf16x8,
                        *(const u16x8*)&Ps[q * 64 + (((ks * 4 + kg) ^ (q & 7)) * 8)]);
                }
#pragma unroll
                for (int nj = 0; nj < 4; ++nj) {
                    int hd = nj * 16 + lr;
                    bv[nj] = __builtin_bit_cast(bf16x8,
                        *(const u16x8*)&Vs[hd * 64 + (((ks * 4 + kg) ^ (hd & 7)) * 8)]);
                }
#pragma unroll
                for (int mi = 0; mi < 2; ++mi)
#pragma unroll
                    for (int nj = 0; nj < 4; ++nj)
                        oacc[mi][nj] = __builtin_amdgcn_mfma_f32_16x16x32_bf16(
                            ap[mi], bv[nj], oacc[mi][nj], 0, 0, 0);
            }
        }
    }

    // epilogue: reduce l across kg-lanes, O /= l, write bf16 [B,S,H*HD]
#pragma unroll
    for (int nj = 0; nj < 2; ++nj) {
        float l = l_acc[nj];
        l += __shfl_xor(l, 16);
        l += __shfl_xor(l, 32);
        if (kg == 0) red[wave * 32 + nj * 16 + lr] = l;
    }
#pragma unroll
    for (int mi = 0; mi < 2; ++mi) {
        f32x4 lv = *(f32x4*)&red[wave * 32 + mi * 16 + kg * 4];
        f32x4 rv;
#pragma unroll
        for (int r = 0; r < 4; ++r) rv[r] = __builtin_amdgcn_rcpf(lv[r]);
#pragma unroll
        for (int nj = 0; nj < 4; ++nj)
#pragma unroll
            for (int r = 0; r < 4; ++r) {
                int q_local = wave * 32 + mi * 16 + kg * 4 + r;
                size_t row = (size_t)b * 1024 + qt * 128 + q_local;
                O[row * 1024 + h * 64 + nj * 16 + lr] =
                    f2bf(oacc[mi][nj][r] * rv[r]);
            }
    }
}

// ---------------------------------------------------------------------------
extern "C" void kernel_launch(void* const* d_in, const int* in_sizes, int n_in,
                              void* d_out, int out_size, void* d_ws, size_t ws_size,
                              hipStream_t stream) {
    const float* x   = (const float*)d_in[0];
    const float* Wq  = (const float*)d_in[1];
    const float* Wk  = (const float*)d_in[2];
    const float* Wv  = (const float*)d_in[3];
    const float* Wqd = (const float*)d_in[4];
    const float* Wkd = (const float*)d_in[5];
    const float* Wvd = (const float*)d_in[6];
    const float* Wo  = (const float*)d_in[7];
    float* out = (float*)d_out;

    char* ws = (char*)d_ws;
    u16*   WTcat  = (u16*)(ws);                    //  6 MB  [3072][1024] bf16
    u16*   WoT    = (u16*)(ws + 6291456);          //  2 MB
    u16*   xb     = (u16*)(ws + 8388608);          // 16 MB  [8192][1024] bf16
    u16*   q_attn = (u16*)(ws + 25165824);         // 16 MB  [B,S,D] bf16 (prescaled)
    u16*   k_attn = (u16*)(ws + 41943040);         // 16 MB  [B,S,D] bf16
    u16*   vT     = (u16*)(ws + 58720256);         // 16 MB  [B,H,64,S]
    u16*   Ow     = (u16*)(ws + 75497472);         // 16 MB  [8192][1024]
    float* part   = (float*)(ws + 92274688);       // 12 MB  partials

    cvt_fused<<<dim3(32, 32, 12), 256, 0, stream>>>(
        Wq, Wk, Wv, Wo, WTcat, WoT, (const float4*)x, xb);
    gemm_qkv<<<dim3(12, 64), 512, 0, stream>>>(xb, WTcat, out, q_attn, k_attn);
    ded_partial<<<dim3(8, 16, 3), 512, 0, stream>>>(x, Wqd, Wkd, Wvd, part);
    fix_vt<<<dim3(2432), 256, 0, stream>>>(
        part, out, q_attn, k_attn, out + (size_t)2 * BSD, vT);
    attn<<<dim3(8, 16, 8), 256, 0, stream>>>(q_attn, k_attn, vT, Ow);
    gemm8p_wo<<<dim3(4, 64), 512, 0, stream>>>(Ow, WoT, out);
}